// Round 1
// baseline (5673.878 us; speedup 1.0000x reference)
//
#include <hip/hip_runtime.h>
#include <math.h>

#define N_  100000
#define P_  96
#define V_  4
#define M_  70000
#define K_  43
#define KC_ 27

// ---------------------------------------------------------------------------
// srcOf[k][dst] = src  (dst unique within each map -> no collisions)
__global__ __launch_bounds__(256) void k_build_srcof(const int* __restrict__ km,
                                                     int* __restrict__ srcOf) {
    int idx = blockIdx.x * 256 + threadIdx.x;
    if (idx >= K_ * M_) return;
    int k = idx / M_;
    int e = idx - k * M_;
    const int* p = km + (size_t)(k * M_ + e) * 2;
    int src = p[0], dst = p[1];
    srcOf[(size_t)k * N_ + dst] = src;
}

// rowAbs[r] = sum_j |x[r][j]|   (one wave per row)
__global__ __launch_bounds__(256) void k_rowabs(const float* __restrict__ x,
                                                float* __restrict__ rowAbs) {
    int row = blockIdx.x * 4 + (threadIdx.x >> 6);
    int lane = threadIdx.x & 63;
    if (row >= N_) return;
    const float* xr = x + (size_t)row * 96;
    float s = 0.f;
    for (int j = lane; j < 96; j += 64) s += fabsf(xr[j]);
#pragma unroll
    for (int o = 32; o > 0; o >>= 1) s += __shfl_down(s, o, 64);
    if (lane == 0) rowAbs[row] = s;
}

// ---------------------------------------------------------------------------
// y[r][:] = sum_{k<27, srcOf[k][r]>=0} x[srcOf[k][r]][:] @ W[k]   (96->96)
// block: 64 rows x 96 ch, 256 threads, 4x6 register tile, W^T + rows in LDS.
__global__ __launch_bounds__(256) void k_conv96(const float* __restrict__ xin,
                                                const float* __restrict__ W,
                                                const int* __restrict__ srcOf,
                                                float* __restrict__ yout) {
    __shared__ __align__(16) float sWt[96 * 100];   // Wt[ch][j], stride 100
    __shared__ __align__(16) float srow[64 * 100];  // rows, stride 100
    __shared__ int ssrc[64];
    int r0 = blockIdx.x * 64;
    int t = threadIdx.x;
    int eg = t & 15;   // edge(row) group -> rows eg*4..+3
    int cg = t >> 4;   // channel group  -> ch cg*6..+5
    float acc[4][6];
#pragma unroll
    for (int e = 0; e < 4; e++)
#pragma unroll
        for (int c = 0; c < 6; c++) acc[e][c] = 0.f;

    for (int k = 0; k < KC_; k++) {
        __syncthreads();
        if (t < 64) {
            int r = r0 + t;
            ssrc[t] = (r < N_) ? srcOf[(size_t)k * N_ + r] : -1;
        }
        for (int p = t; p < 96 * 96; p += 256) {
            int j = p / 96, ch = p - j * 96;
            sWt[ch * 100 + j] = W[(size_t)k * 9216 + p];
        }
        __syncthreads();
        for (int p = t; p < 64 * 96; p += 256) {
            int e = p / 96, j = p - e * 96;
            int s = ssrc[e];
            srow[e * 100 + j] = (s >= 0) ? xin[(size_t)s * 96 + j] : 0.f;
        }
        __syncthreads();
#pragma unroll 2
        for (int j0 = 0; j0 < 96; j0 += 4) {
            float4 xv[4], wv[6];
#pragma unroll
            for (int e = 0; e < 4; e++)
                xv[e] = *(const float4*)&srow[(eg * 4 + e) * 100 + j0];
#pragma unroll
            for (int c = 0; c < 6; c++)
                wv[c] = *(const float4*)&sWt[(cg * 6 + c) * 100 + j0];
#pragma unroll
            for (int e = 0; e < 4; e++)
#pragma unroll
                for (int c = 0; c < 6; c++)
                    acc[e][c] += xv[e].x * wv[c].x + xv[e].y * wv[c].y +
                                 xv[e].z * wv[c].z + xv[e].w * wv[c].w;
        }
    }
#pragma unroll
    for (int e = 0; e < 4; e++) {
        int r = r0 + eg * 4 + e;
        if (r < N_) {
#pragma unroll
            for (int c = 0; c < 6; c++)
                yout[(size_t)r * 96 + cg * 6 + c] = acc[e][c];
        }
    }
}

// y[r][c] = sum_k x[srcOf[k][r]][:] @ W[k][:,c]   (96->4), 48 rows/block
__global__ __launch_bounds__(192) void k_conv4(const float* __restrict__ xin,
                                               const float* __restrict__ W,
                                               const int* __restrict__ srcOf,
                                               float* __restrict__ yout) {
    __shared__ __align__(16) float sW2[KC_ * 4 * 96];  // [k][c][j]
    __shared__ __align__(16) float srow[48 * 100];
    __shared__ int ssrc[48];
    int r0 = blockIdx.x * 48;
    int t = threadIdx.x;
    int e = t >> 2;   // 0..47
    int c = t & 3;
    for (int p = t; p < KC_ * 4 * 96; p += 192) {
        int k = p / 384;
        int rem = p - k * 384;
        int j = rem >> 2, cc = rem & 3;
        sW2[k * 384 + cc * 96 + j] = W[p];
    }
    float acc = 0.f;
    for (int k = 0; k < KC_; k++) {
        __syncthreads();
        if (t < 48) {
            int r = r0 + t;
            ssrc[t] = (r < N_) ? srcOf[(size_t)k * N_ + r] : -1;
        }
        __syncthreads();
        for (int p = t; p < 48 * 96; p += 192) {
            int ee = p / 96, j = p - ee * 96;
            int s = ssrc[ee];
            srow[ee * 100 + j] = (s >= 0) ? xin[(size_t)s * 96 + j] : 0.f;
        }
        __syncthreads();
        const float* wk = &sW2[k * 384 + c * 96];
        const float* xr = &srow[e * 100];
#pragma unroll 4
        for (int j0 = 0; j0 < 96; j0 += 4) {
            float4 xv = *(const float4*)&xr[j0];
            float4 wv = *(const float4*)&wk[j0];
            acc += xv.x * wv.x + xv.y * wv.y + xv.z * wv.z + xv.w * wv.w;
        }
    }
    int r = r0 + e;
    if (r < N_) yout[(size_t)r * 4 + c] = acc;
}

// ---------------------------------------------------------------------------
// BN stats: stats[ch] += sum, stats[96+ch] += sumsq
__global__ __launch_bounds__(192) void k_bnstats96(const float* __restrict__ xin,
                                                   float* __restrict__ stats) {
    __shared__ float sS[192], sQ[192];
    int t = threadIdx.x;
    int ch = t % 96, half = t / 96;
    float s = 0.f, q = 0.f;
    for (int r = blockIdx.x * 2 + half; r < N_; r += gridDim.x * 2) {
        float v = xin[(size_t)r * 96 + ch];
        s += v; q += v * v;
    }
    sS[t] = s; sQ[t] = q;
    __syncthreads();
    if (t < 96) {
        atomicAdd(&stats[ch], sS[t] + sS[t + 96]);
        atomicAdd(&stats[96 + ch], sQ[t] + sQ[t + 96]);
    }
}

__global__ __launch_bounds__(256) void k_bnstats4(const float* __restrict__ xin,
                                                  float* __restrict__ stats) {
    __shared__ float sS[256], sQ[256];
    int t = threadIdx.x;
    int c = t & 3, sub = t >> 2;
    float s = 0.f, q = 0.f;
    for (int r = blockIdx.x * 64 + sub; r < N_; r += gridDim.x * 64) {
        float v = xin[(size_t)r * 4 + c];
        s += v; q += v * v;
    }
    sS[t] = s; sQ[t] = q;
    __syncthreads();
    for (int off = 128; off >= 4; off >>= 1) {
        if (t < off) { sS[t] += sS[t + off]; sQ[t] += sQ[t + off]; }
        __syncthreads();
    }
    if (t < 4) {
        atomicAdd(&stats[t], sS[t]);
        atomicAdd(&stats[96 + t], sQ[t]);
    }
}

// MODE 0: y=relu(bn)   MODE 1: y=relu(bn)+aux_pe_repeat   MODE 2: y=relu(bn)+aux
template <int C, int MODE>
__global__ __launch_bounds__(256) void k_bnapply(float* __restrict__ y,
                                                 const float* __restrict__ stats,
                                                 const float* __restrict__ g,
                                                 const float* __restrict__ b,
                                                 const float* __restrict__ aux) {
    int idx = blockIdx.x * 256 + threadIdx.x;
    if (idx >= N_ * C) return;
    int ch = idx % C;
    float mean = stats[ch] * (1.f / N_);
    float var = stats[96 + ch] * (1.f / N_) - mean * mean;
    float scale = g[ch] * rsqrtf(fmaxf(var, 0.f) + 1e-5f);
    float v = (y[idx] - mean) * scale + b[ch];
    v = fmaxf(v, 0.f);
    if (MODE == 1) { int r = idx / C; v += aux[(size_t)r * 4 + (ch / 24)]; }
    if (MODE == 2) { v += aux[idx]; }
    y[idx] = v;
}

// pe chain
__global__ __launch_bounds__(256) void k_pe1(const float* __restrict__ coords,
                                             const float* __restrict__ Wp1,
                                             float* __restrict__ out) {
    int idx = blockIdx.x * 256 + threadIdx.x;
    if (idx >= N_ * 96) return;
    int r = idx / 96, ch = idx - r * 96;
    float c0 = coords[r * 3], c1 = coords[r * 3 + 1], c2 = coords[r * 3 + 2];
    out[idx] = c0 * Wp1[ch] + c1 * Wp1[96 + ch] + c2 * Wp1[192 + ch];
}

__global__ __launch_bounds__(256) void k_pe2(const float* __restrict__ hin,
                                             const float* __restrict__ Wp2,
                                             float* __restrict__ out) {
    int idx = blockIdx.x * 256 + threadIdx.x;
    if (idx >= N_ * 4) return;
    int r = idx / 4, c = idx & 3;
    const float* hr = hin + (size_t)r * 96;
    float acc = 0.f;
#pragma unroll 4
    for (int j = 0; j < 96; j++) acc += hr[j] * Wp2[j * 4 + c];
    out[idx] = acc;
}

// ---------------------------------------------------------------------------
// Per-row fused attention: logits (43x4) -> softmax over k -> weighted gather
__global__ __launch_bounds__(64) void k_attn_out(
    const float* __restrict__ qf, const float* __restrict__ vf,
    const int* __restrict__ srcOf, const float* __restrict__ rowAbs,
    const float* __restrict__ W1, const float* __restrict__ b1,
    const float* __restrict__ W2, const float* __restrict__ b2,
    float* __restrict__ out) {
    int r = blockIdx.x;
    int t = threadIdx.x;
    __shared__ int ssrc[K_];
    __shared__ float smk[K_];
    __shared__ float slog[K_][V_];
    __shared__ float sa[K_][V_];
    __shared__ float sqf[V_];
    __shared__ __align__(16) float sW1t[96 * 4];  // [j][c]
    __shared__ __align__(16) float sW2[96 * 4];   // [j][c]
    __shared__ float sb1[96];

    for (int p = t; p < 384; p += 64) {
        sW1t[p] = W1[(p & 3) * 96 + (p >> 2)];
        sW2[p] = W2[p];
    }
    for (int p = t; p < 96; p += 64) sb1[p] = b1[p];
    if (t < K_) {
        int s = srcOf[(size_t)t * N_ + r];
        ssrc[t] = s;
        smk[t] = (s >= 0 && rowAbs[s] > 0.f) ? 1.f : 0.f;
    }
    if (t < 4) sqf[t] = qf[(size_t)r * 4 + t];
    __syncthreads();

    if (t < K_) {
        float l0 = 0.f, l1 = 0.f, l2 = 0.f, l3 = 0.f;
        if (smk[t] > 0.f) {
            int s = ssrc[t];
            float d0 = qf[(size_t)s * 4 + 0] - sqf[0];
            float d1 = qf[(size_t)s * 4 + 1] - sqf[1];
            float d2 = qf[(size_t)s * 4 + 2] - sqf[2];
            float d3 = qf[(size_t)s * 4 + 3] - sqf[3];
#pragma unroll 4
            for (int j = 0; j < 96; j++) {
                float4 w1 = *(const float4*)&sW1t[j * 4];
                float h = sb1[j] + d0 * w1.x + d1 * w1.y + d2 * w1.z + d3 * w1.w;
                h = fmaxf(h, 0.f);
                float4 w2 = *(const float4*)&sW2[j * 4];
                l0 += h * w2.x; l1 += h * w2.y; l2 += h * w2.z; l3 += h * w2.w;
            }
            l0 += b2[0]; l1 += b2[1]; l2 += b2[2]; l3 += b2[3];
        }
        slog[t][0] = l0; slog[t][1] = l1; slog[t][2] = l2; slog[t][3] = l3;
    }
    __syncthreads();

    if (t < 4) {  // softmax over all 43 entries (uncovered contribute exp(0))
        float mx = -1e30f;
        for (int k = 0; k < K_; k++) mx = fmaxf(mx, slog[k][t]);
        float den = 0.f;
        for (int k = 0; k < K_; k++) den += __expf(slog[k][t] - mx);
        float inv = 1.f / den;
        for (int k = 0; k < K_; k++) sa[k][t] = __expf(slog[k][t] - mx) * inv;
    }
    __syncthreads();

    for (int ch = t; ch < 96; ch += 64) {
        int cg = ch / 24;
        float acc = 0.f;
        for (int k = 0; k < K_; k++) {
            if (smk[k] > 0.f) {
                int idxk = (k < 27) ? k : ((k < 35) ? (k - 27) : (k - 35));
                acc += vf[(size_t)ssrc[k] * 96 + ch] * sa[idxk][cg];
            }
        }
        out[(size_t)r * 96 + ch] = acc;
    }
}

// ---------------------------------------------------------------------------
extern "C" void kernel_launch(void* const* d_in, const int* in_sizes, int n_in,
                              void* d_out, int out_size, void* d_ws, size_t ws_size,
                              hipStream_t stream) {
    const float* x      = (const float*)d_in[0];
    const float* coords = (const float*)d_in[1];
    const float* Wq1 = (const float*)d_in[2];
    const float* gq1 = (const float*)d_in[3];
    const float* bq1 = (const float*)d_in[4];
    const float* Wq2 = (const float*)d_in[5];
    const float* gq2 = (const float*)d_in[6];
    const float* bq2 = (const float*)d_in[7];
    const float* Wv  = (const float*)d_in[8];
    const float* gv  = (const float*)d_in[9];
    const float* bv  = (const float*)d_in[10];
    const float* Wp1 = (const float*)d_in[11];
    const float* gp1 = (const float*)d_in[12];
    const float* bp1 = (const float*)d_in[13];
    const float* Wp2 = (const float*)d_in[14];
    const float* gp2 = (const float*)d_in[15];
    const float* bp2 = (const float*)d_in[16];
    const float* W1  = (const float*)d_in[17];
    const float* b1  = (const float*)d_in[18];
    const float* W2  = (const float*)d_in[19];
    const float* b2  = (const float*)d_in[20];
    const float* g_out = (const float*)d_in[21];
    const float* b_out = (const float*)d_in[22];
    const int* kmaps = (const int*)d_in[23];
    float* out = (float*)d_out;

    char* ws = (char*)d_ws;
    int*   srcOf  = (int*)ws;                       // 43*N*4   = 17,200,000
    float* rowAbs = (float*)(ws + 17200000);        // N*4      =    400,000
    float* bufA   = (float*)(ws + 17600000);        // N*96*4   = 38,400,000
    float* bufB   = (float*)(ws + 56000000);        // N*96*4   = 38,400,000
    float* qf     = (float*)(ws + 94400000);        // N*4*4    =  1,600,000
    float* peb    = (float*)(ws + 96000000);        // N*4*4    =  1,600,000
    float* stats  = (float*)(ws + 97600000);        // 6*192*4  =      4,608

    hipMemsetAsync(srcOf, 0xFF, (size_t)K_ * N_ * 4, stream);  // -1
    hipMemsetAsync(stats, 0, 6 * 192 * 4, stream);

    k_build_srcof<<<(K_ * M_ + 255) / 256, 256, 0, stream>>>(kmaps, srcOf);
    k_rowabs<<<(N_ + 3) / 4, 256, 0, stream>>>(x, rowAbs);

    const int cb96 = (N_ + 63) / 64;   // 1563
    const int cb4  = (N_ + 47) / 48;   // 2084
    const int eb96 = (N_ * 96 + 255) / 256;
    const int eb4  = (N_ * 4 + 255) / 256;

    // qf = cbr(cbr(x, Wq1), Wq2)
    k_conv96<<<cb96, 256, 0, stream>>>(x, Wq1, srcOf, bufA);
    k_bnstats96<<<512, 192, 0, stream>>>(bufA, stats + 0 * 192);
    k_bnapply<96, 0><<<eb96, 256, 0, stream>>>(bufA, stats + 0 * 192, gq1, bq1, nullptr);
    k_conv4<<<cb4, 192, 0, stream>>>(bufA, Wq2, srcOf, qf);
    k_bnstats4<<<512, 256, 0, stream>>>(qf, stats + 1 * 192);
    k_bnapply<4, 0><<<eb4, 256, 0, stream>>>(qf, stats + 1 * 192, gq2, bq2, nullptr);

    // pe = relu(bn(relu(bn(coords@Wp1)) @ Wp2))
    k_pe1<<<eb96, 256, 0, stream>>>(coords, Wp1, bufB);
    k_bnstats96<<<512, 192, 0, stream>>>(bufB, stats + 2 * 192);
    k_bnapply<96, 0><<<eb96, 256, 0, stream>>>(bufB, stats + 2 * 192, gp1, bp1, nullptr);
    k_pe2<<<eb4, 256, 0, stream>>>(bufB, Wp2, peb);
    k_bnstats4<<<512, 256, 0, stream>>>(peb, stats + 3 * 192);
    k_bnapply<4, 0><<<eb4, 256, 0, stream>>>(peb, stats + 3 * 192, gp2, bp2, nullptr);

    // v_f = cbr(x, Wv) + repeat(pe, 24)
    k_conv96<<<cb96, 256, 0, stream>>>(x, Wv, srcOf, bufB);
    k_bnstats96<<<512, 192, 0, stream>>>(bufB, stats + 4 * 192);
    k_bnapply<96, 1><<<eb96, 256, 0, stream>>>(bufB, stats + 4 * 192, gv, bv, peb);

    // attention + weighted gather accumulate
    k_attn_out<<<N_, 64, 0, stream>>>(qf, bufB, srcOf, rowAbs, W1, b1, W2, b2, out);

    // out = relu(bn(out)) + x
    k_bnstats96<<<512, 192, 0, stream>>>(out, stats + 5 * 192);
    k_bnapply<96, 2><<<eb96, 256, 0, stream>>>(out, stats + 5 * 192, g_out, b_out, x);
}

// Round 3
// 1543.010 us; speedup vs baseline: 3.6771x; 3.6771x over previous
//
#include <hip/hip_runtime.h>
#include <math.h>

#define N_  100000
#define P_  96
#define V_  4
#define M_  70000
#define K_  43
#define KC_ 27

typedef unsigned short u16;
typedef __attribute__((ext_vector_type(8))) short bf16x8;
typedef __attribute__((ext_vector_type(4))) float f32x4;

__device__ __forceinline__ u16 f2bf(float f) {
    unsigned int u = __float_as_uint(f);
    u += 0x7fffu + ((u >> 16) & 1u);   // round-to-nearest-even
    return (u16)(u >> 16);
}

// ---------------------------------------------------------------------------
// srcOf[k][dst] = src  (dst unique within each map -> no collisions)
__global__ __launch_bounds__(256) void k_build_srcof(const int* __restrict__ km,
                                                     int* __restrict__ srcOf) {
    int idx = blockIdx.x * 256 + threadIdx.x;
    if (idx >= K_ * M_) return;
    int k = idx / M_;
    int e = idx - k * M_;
    const int* p = km + (size_t)(k * M_ + e) * 2;
    srcOf[(size_t)k * N_ + p[1]] = p[0];
}

// rowAbs[r] = sum_j |x[r][j]|
__global__ __launch_bounds__(256) void k_rowabs(const float* __restrict__ x,
                                                float* __restrict__ rowAbs) {
    int row = blockIdx.x * 4 + (threadIdx.x >> 6);
    int lane = threadIdx.x & 63;
    if (row >= N_) return;
    const float* xr = x + (size_t)row * 96;
    float s = 0.f;
    for (int j = lane; j < 96; j += 64) s += fabsf(xr[j]);
#pragma unroll
    for (int o = 32; o > 0; o >>= 1) s += __shfl_down(s, o, 64);
    if (lane == 0) rowAbs[row] = s;
}

// x (f32) -> xb (bf16)
__global__ __launch_bounds__(256) void k_cvt_bf16(const float* __restrict__ x,
                                                  u16* __restrict__ xb, int n) {
    int idx = blockIdx.x * 256 + threadIdx.x;
    if (idx < n) xb[idx] = f2bf(x[idx]);
}

// Wt[k][n][j] = bf16(W[k][j][n])   (27 x 96 x 96)
__global__ __launch_bounds__(256) void k_wt96(const float* __restrict__ W,
                                              u16* __restrict__ Wt) {
    int idx = blockIdx.x * 256 + threadIdx.x;
    if (idx >= KC_ * 96 * 96) return;
    int k = idx / 9216, rem = idx - k * 9216, n = rem / 96, j = rem - n * 96;
    Wt[idx] = f2bf(W[(size_t)k * 9216 + j * 96 + n]);
}

// Wt4[k][n][j] = bf16(W[k][j][n]) for n<4 else 0   (27 x 16 x 96)
__global__ __launch_bounds__(256) void k_wt4(const float* __restrict__ W,
                                             u16* __restrict__ Wt) {
    int idx = blockIdx.x * 256 + threadIdx.x;
    if (idx >= KC_ * 16 * 96) return;
    int k = idx / 1536, rem = idx - k * 1536, n = rem / 96, j = rem - n * 96;
    Wt[idx] = (n < 4) ? f2bf(W[(size_t)k * 384 + j * 4 + n]) : (u16)0;
}

// ---------------------------------------------------------------------------
// y[r][:] = sum_k x[srcOf[k][r]][:] @ W[k]  via bf16 MFMA. 64 rows/block.
__global__ __launch_bounds__(256) void k_conv96_mfma(
    const u16* __restrict__ xb, const u16* __restrict__ Wt,
    const int* __restrict__ srcOf, float* __restrict__ yout) {
    __shared__ u16 sA[64 * 104];   // gathered rows, stride 104 (2-way worst)
    __shared__ u16 sB[96 * 104];   // Wt[n][k]
    const int r0 = blockIdx.x * 64;
    const int t = threadIdx.x;
    const int wv = t >> 6, lane = t & 63;
    const int m = lane & 15, quad = lane >> 4;
    const int ea = t >> 2, jca = (t & 3) * 3;  // A staging: row ea, 3 chunks
    f32x4 acc[6];
#pragma unroll
    for (int i = 0; i < 6; i++) acc[i] = (f32x4){0.f, 0.f, 0.f, 0.f};

    for (int k = 0; k < KC_; k++) {
        __syncthreads();
        {   // stage A: 64 rows x 96 bf16, gathered
            int r = r0 + ea;
            int src = (r < N_) ? srcOf[(size_t)k * N_ + r] : -1;
            if (src >= 0) {
                const uint4* sp = (const uint4*)(xb + (size_t)src * 96);
#pragma unroll
                for (int i = 0; i < 3; i++)
                    *(uint4*)(sA + ea * 104 + (jca + i) * 8) = sp[jca + i];
            } else {
                uint4 z = make_uint4(0, 0, 0, 0);
#pragma unroll
                for (int i = 0; i < 3; i++)
                    *(uint4*)(sA + ea * 104 + (jca + i) * 8) = z;
            }
        }
        {   // stage B: 96 x 96 bf16, contiguous
            const u16* wk = Wt + (size_t)k * 9216;
#pragma unroll
            for (int i = 0; i < 5; i++) {
                int c = t + 256 * i;
                if (c < 1152) {
                    int n = c / 12, jc = c - n * 12;
                    *(uint4*)(sB + n * 104 + jc * 8) =
                        *(const uint4*)(wk + n * 96 + jc * 8);
                }
            }
        }
        __syncthreads();
#pragma unroll
        for (int kk = 0; kk < 3; kk++) {
            bf16x8 af = *(const bf16x8*)(sA + (wv * 16 + m) * 104 + kk * 32 + quad * 8);
#pragma unroll
            for (int nt = 0; nt < 6; nt++) {
                bf16x8 bfr = *(const bf16x8*)(sB + (nt * 16 + m) * 104 + kk * 32 + quad * 8);
                acc[nt] = __builtin_amdgcn_mfma_f32_16x16x32_bf16(af, bfr, acc[nt], 0, 0, 0);
            }
        }
    }
#pragma unroll
    for (int nt = 0; nt < 6; nt++) {
#pragma unroll
        for (int rg = 0; rg < 4; rg++) {
            int r = r0 + wv * 16 + quad * 4 + rg;
            if (r < N_) yout[(size_t)r * 96 + nt * 16 + m] = acc[nt][rg];
        }
    }
}

// 96->4 conv via MFMA (N padded to 16). 128 rows/block.
__global__ __launch_bounds__(256) void k_conv4_mfma(
    const u16* __restrict__ xbA, const u16* __restrict__ Wt4,
    const int* __restrict__ srcOf, float* __restrict__ qf) {
    __shared__ u16 sA[128 * 104];
    __shared__ u16 sB[16 * 104];
    const int r0 = blockIdx.x * 128;
    const int t = threadIdx.x;
    const int wv = t >> 6, lane = t & 63;
    const int m = lane & 15, quad = lane >> 4;
    const int ea = t >> 1, jca = (t & 1) * 6;
    f32x4 acc[2];
    acc[0] = (f32x4){0.f, 0.f, 0.f, 0.f};
    acc[1] = (f32x4){0.f, 0.f, 0.f, 0.f};
    for (int k = 0; k < KC_; k++) {
        __syncthreads();
        {
            int r = r0 + ea;
            int src = (r < N_) ? srcOf[(size_t)k * N_ + r] : -1;
            if (src >= 0) {
                const uint4* sp = (const uint4*)(xbA + (size_t)src * 96);
#pragma unroll
                for (int i = 0; i < 6; i++)
                    *(uint4*)(sA + ea * 104 + (jca + i) * 8) = sp[jca + i];
            } else {
                uint4 z = make_uint4(0, 0, 0, 0);
#pragma unroll
                for (int i = 0; i < 6; i++)
                    *(uint4*)(sA + ea * 104 + (jca + i) * 8) = z;
            }
        }
        if (t < 192) {
            int n = t / 12, jc = t - (t / 12) * 12;
            *(uint4*)(sB + n * 104 + jc * 8) =
                *(const uint4*)(Wt4 + (size_t)k * 1536 + n * 96 + jc * 8);
        }
        __syncthreads();
#pragma unroll
        for (int kk = 0; kk < 3; kk++) {
            bf16x8 bfr = *(const bf16x8*)(sB + m * 104 + kk * 32 + quad * 8);
#pragma unroll
            for (int rt = 0; rt < 2; rt++) {
                bf16x8 af = *(const bf16x8*)(sA + ((wv * 2 + rt) * 16 + m) * 104 + kk * 32 + quad * 8);
                acc[rt] = __builtin_amdgcn_mfma_f32_16x16x32_bf16(af, bfr, acc[rt], 0, 0, 0);
            }
        }
    }
    if (m < 4) {
#pragma unroll
        for (int rt = 0; rt < 2; rt++)
#pragma unroll
            for (int rg = 0; rg < 4; rg++) {
                int r = r0 + (wv * 2 + rt) * 16 + quad * 4 + rg;
                if (r < N_) qf[(size_t)r * 4 + m] = acc[rt][rg];
            }
    }
}

// ---------------------------------------------------------------------------
__global__ __launch_bounds__(192) void k_bnstats96(const float* __restrict__ xin,
                                                   float* __restrict__ stats) {
    __shared__ float sS[192], sQ[192];
    int t = threadIdx.x;
    int ch = t % 96, half = t / 96;
    float s = 0.f, q = 0.f;
    for (int r = blockIdx.x * 2 + half; r < N_; r += gridDim.x * 2) {
        float v = xin[(size_t)r * 96 + ch];
        s += v; q += v * v;
    }
    sS[t] = s; sQ[t] = q;
    __syncthreads();
    if (t < 96) {
        atomicAdd(&stats[ch], sS[t] + sS[t + 96]);
        atomicAdd(&stats[96 + ch], sQ[t] + sQ[t + 96]);
    }
}

__global__ __launch_bounds__(256) void k_bnstats4(const float* __restrict__ xin,
                                                  float* __restrict__ stats) {
    __shared__ float sS[256], sQ[256];
    int t = threadIdx.x;
    int c = t & 3, sub = t >> 2;
    float s = 0.f, q = 0.f;
    for (int r = blockIdx.x * 64 + sub; r < N_; r += gridDim.x * 64) {
        float v = xin[(size_t)r * 4 + c];
        s += v; q += v * v;
    }
    sS[t] = s; sQ[t] = q;
    __syncthreads();
    for (int off = 128; off >= 4; off >>= 1) {
        if (t < off) { sS[t] += sS[t + off]; sQ[t] += sQ[t + off]; }
        __syncthreads();
    }
    if (t < 4) {
        atomicAdd(&stats[t], sS[t]);
        atomicAdd(&stats[96 + t], sQ[t]);
    }
}

// MODE 0: relu(bn)  MODE 1: relu(bn)+pe_repeat  MODE 2: relu(bn)+aux
template <int C, int MODE, int BF16OUT>
__global__ __launch_bounds__(256) void k_bnapply(float* __restrict__ y,
                                                 const float* __restrict__ stats,
                                                 const float* __restrict__ g,
                                                 const float* __restrict__ b,
                                                 const float* __restrict__ aux,
                                                 u16* __restrict__ ybf) {
    int idx = blockIdx.x * 256 + threadIdx.x;
    if (idx >= N_ * C) return;
    int ch = idx % C;
    float mean = stats[ch] * (1.f / N_);
    float var = stats[96 + ch] * (1.f / N_) - mean * mean;
    float scale = g[ch] * rsqrtf(fmaxf(var, 0.f) + 1e-5f);
    float v = (y[idx] - mean) * scale + b[ch];
    v = fmaxf(v, 0.f);
    if (MODE == 1) { int r = idx / C; v += aux[(size_t)r * 4 + (ch / 24)]; }
    if (MODE == 2) { v += aux[idx]; }
    y[idx] = v;
    if (BF16OUT) ybf[idx] = f2bf(v);
}

__global__ __launch_bounds__(256) void k_pe1(const float* __restrict__ coords,
                                             const float* __restrict__ Wp1,
                                             float* __restrict__ out) {
    int idx = blockIdx.x * 256 + threadIdx.x;
    if (idx >= N_ * 96) return;
    int r = idx / 96, ch = idx - r * 96;
    float c0 = coords[r * 3], c1 = coords[r * 3 + 1], c2 = coords[r * 3 + 2];
    out[idx] = c0 * Wp1[ch] + c1 * Wp1[96 + ch] + c2 * Wp1[192 + ch];
}

__global__ __launch_bounds__(256) void k_pe2(const float* __restrict__ hin,
                                             const float* __restrict__ Wp2,
                                             float* __restrict__ out) {
    int idx = blockIdx.x * 256 + threadIdx.x;
    if (idx >= N_ * 4) return;
    int r = idx / 4, c = idx & 3;
    const float* hr = hin + (size_t)r * 96;
    float acc = 0.f;
#pragma unroll 4
    for (int j = 0; j < 96; j++) acc += hr[j] * Wp2[j * 4 + c];
    out[idx] = acc;
}

// ---------------------------------------------------------------------------
// Fused attention: 4 rows/block (1 row per wave), W1/W2 shared in LDS.
__global__ __launch_bounds__(256) void k_attn_out(
    const float* __restrict__ qf, const float* __restrict__ vf,
    const int* __restrict__ srcOf, const float* __restrict__ rowAbs,
    const float* __restrict__ W1, const float* __restrict__ b1,
    const float* __restrict__ W2, const float* __restrict__ b2,
    float* __restrict__ out) {
    const int t = threadIdx.x;
    const int wv = t >> 6, lane = t & 63;
    const int r = blockIdx.x * 4 + wv;   // N_ % 4 == 0, always valid
    __shared__ float sW1t[384], sW2[384], sb1[96], sb2[4];
    __shared__ int ssrc[4][K_];
    __shared__ float smk[4][K_];
    __shared__ float slog[4][K_][V_];
    __shared__ float sa[4][K_][V_];
    __shared__ float sqf[4][V_];

    for (int p = t; p < 384; p += 256) {
        sW1t[p] = W1[(p & 3) * 96 + (p >> 2)];
        sW2[p] = W2[p];
    }
    if (t < 96) sb1[t] = b1[t];
    if (t < 4) sb2[t] = b2[t];
    if (lane < K_) {
        int s = srcOf[(size_t)lane * N_ + r];
        ssrc[wv][lane] = s;
        smk[wv][lane] = (s >= 0 && rowAbs[s] > 0.f) ? 1.f : 0.f;
    }
    if (lane < 4) sqf[wv][lane] = qf[(size_t)r * 4 + lane];
    __syncthreads();

    if (lane < K_) {
        float l0 = 0.f, l1 = 0.f, l2 = 0.f, l3 = 0.f;
        if (smk[wv][lane] > 0.f) {
            int s = ssrc[wv][lane];
            float4 qs = *(const float4*)(qf + (size_t)s * 4);
            float d0 = qs.x - sqf[wv][0], d1 = qs.y - sqf[wv][1];
            float d2 = qs.z - sqf[wv][2], d3 = qs.w - sqf[wv][3];
#pragma unroll 4
            for (int j = 0; j < 96; j++) {
                float4 w1 = *(const float4*)&sW1t[j * 4];
                float h = sb1[j] + d0 * w1.x + d1 * w1.y + d2 * w1.z + d3 * w1.w;
                h = fmaxf(h, 0.f);
                float4 w2 = *(const float4*)&sW2[j * 4];
                l0 += h * w2.x; l1 += h * w2.y; l2 += h * w2.z; l3 += h * w2.w;
            }
            l0 += sb2[0]; l1 += sb2[1]; l2 += sb2[2]; l3 += sb2[3];
        }
        slog[wv][lane][0] = l0; slog[wv][lane][1] = l1;
        slog[wv][lane][2] = l2; slog[wv][lane][3] = l3;
    }
    __syncthreads();

    if (lane < 4) {  // softmax over all 43 (uncovered contribute exp(0))
        float mx = 0.f;
        for (int k = 0; k < K_; k++) mx = fmaxf(mx, slog[wv][k][lane]);
        float den = 0.f;
        for (int k = 0; k < K_; k++) den += __expf(slog[wv][k][lane] - mx);
        float inv = 1.f / den;
        for (int k = 0; k < K_; k++)
            sa[wv][k][lane] = __expf(slog[wv][k][lane] - mx) * inv;
    }
    __syncthreads();

    for (int ch = lane; ch < 96; ch += 64) {
        int cg = ch / 24;
        float acc = 0.f;
        for (int k = 0; k < K_; k++) {
            if (smk[wv][k] > 0.f) {
                int idxk = (k < 27) ? k : ((k < 35) ? (k - 27) : (k - 35));
                acc += vf[(size_t)ssrc[wv][k] * 96 + ch] * sa[wv][idxk][cg];
            }
        }
        out[(size_t)r * 96 + ch] = acc;
    }
}

// ---------------------------------------------------------------------------
extern "C" void kernel_launch(void* const* d_in, const int* in_sizes, int n_in,
                              void* d_out, int out_size, void* d_ws, size_t ws_size,
                              hipStream_t stream) {
    const float* x      = (const float*)d_in[0];
    const float* coords = (const float*)d_in[1];
    const float* Wq1 = (const float*)d_in[2];
    const float* gq1 = (const float*)d_in[3];
    const float* bq1 = (const float*)d_in[4];
    const float* Wq2 = (const float*)d_in[5];
    const float* gq2 = (const float*)d_in[6];
    const float* bq2 = (const float*)d_in[7];
    const float* Wv  = (const float*)d_in[8];
    const float* gv  = (const float*)d_in[9];
    const float* bv  = (const float*)d_in[10];
    const float* Wp1 = (const float*)d_in[11];
    const float* gp1 = (const float*)d_in[12];
    const float* bp1 = (const float*)d_in[13];
    const float* Wp2 = (const float*)d_in[14];
    const float* gp2 = (const float*)d_in[15];
    const float* bp2 = (const float*)d_in[16];
    const float* W1  = (const float*)d_in[17];
    const float* b1  = (const float*)d_in[18];
    const float* W2  = (const float*)d_in[19];
    const float* b2  = (const float*)d_in[20];
    const float* g_out = (const float*)d_in[21];
    const float* b_out = (const float*)d_in[22];
    const int* kmaps = (const int*)d_in[23];
    float* out = (float*)d_out;

    char* ws = (char*)d_ws;
    int*   srcOf  = (int*)ws;                        //  0          + 17,200,000
    float* rowAbs = (float*)(ws + 17200000);         //             +    400,000
    float* bufA   = (float*)(ws + 17600000);         //             + 38,400,000
    u16*   bufAb  = (u16*)(ws + 56000000);           //             + 19,200,000
    u16*   xb     = (u16*)(ws + 75200000);           //             + 19,200,000
    float* qf     = (float*)(ws + 94400000);         //             +  1,600,000
    float* peb    = (float*)(ws + 96000000);         //             +  1,600,000
    u16*   Wq1t   = (u16*)(ws + 97600000);           //             +    497,664
    u16*   Wvt    = (u16*)(ws + 98097664);           //             +    497,664
    u16*   Wq2t   = (u16*)(ws + 98595328);           //             +     82,944
    float* stats  = (float*)(ws + 98678272);         //             +      4,608

    hipMemsetAsync(srcOf, 0xFF, (size_t)K_ * N_ * 4, stream);  // -1
    hipMemsetAsync(stats, 0, 6 * 192 * 4, stream);

    k_build_srcof<<<(K_ * M_ + 255) / 256, 256, 0, stream>>>(kmaps, srcOf);
    k_rowabs<<<N_ / 4, 256, 0, stream>>>(x, rowAbs);
    k_cvt_bf16<<<N_ * 96 / 256, 256, 0, stream>>>(x, xb, N_ * 96);
    k_wt96<<<(KC_ * 9216 + 255) / 256, 256, 0, stream>>>(Wq1, Wq1t);
    k_wt96<<<(KC_ * 9216 + 255) / 256, 256, 0, stream>>>(Wv, Wvt);
    k_wt4<<<(KC_ * 1536 + 255) / 256, 256, 0, stream>>>(Wq2, Wq2t);

    const int cb96 = (N_ + 63) / 64;     // 1563
    const int cb4  = (N_ + 127) / 128;   // 782
    const int eb96 = N_ * 96 / 256;      // 37500
    const int eb4  = (N_ * 4 + 255) / 256;

    // qf = cbr(cbr(x, Wq1), Wq2)
    k_conv96_mfma<<<cb96, 256, 0, stream>>>(xb, Wq1t, srcOf, bufA);
    k_bnstats96<<<512, 192, 0, stream>>>(bufA, stats + 0 * 192);
    k_bnapply<96, 0, 1><<<eb96, 256, 0, stream>>>(bufA, stats + 0 * 192, gq1, bq1, nullptr, bufAb);
    k_conv4_mfma<<<cb4, 256, 0, stream>>>(bufAb, Wq2t, srcOf, qf);
    k_bnstats4<<<512, 256, 0, stream>>>(qf, stats + 1 * 192);
    k_bnapply<4, 0, 0><<<eb4, 256, 0, stream>>>(qf, stats + 1 * 192, gq2, bq2, nullptr, nullptr);

    // pe chain (bufA reused as scratch; conv4 already consumed bufAb)
    k_pe1<<<eb96, 256, 0, stream>>>(coords, Wp1, bufA);
    k_bnstats96<<<512, 192, 0, stream>>>(bufA, stats + 2 * 192);
    k_bnapply<96, 0, 0><<<eb96, 256, 0, stream>>>(bufA, stats + 2 * 192, gp1, bp1, nullptr, nullptr);
    k_pe2<<<eb4, 256, 0, stream>>>(bufA, Wp2, peb);
    k_bnstats4<<<512, 256, 0, stream>>>(peb, stats + 3 * 192);
    k_bnapply<4, 0, 0><<<eb4, 256, 0, stream>>>(peb, stats + 3 * 192, gp2, bp2, nullptr, nullptr);

    // v_f = cbr(x, Wv) + repeat(pe, 24)   (bufA reused again)
    k_conv96_mfma<<<cb96, 256, 0, stream>>>(xb, Wvt, srcOf, bufA);
    k_bnstats96<<<512, 192, 0, stream>>>(bufA, stats + 4 * 192);
    k_bnapply<96, 1, 0><<<eb96, 256, 0, stream>>>(bufA, stats + 4 * 192, gv, bv, peb, nullptr);

    // attention + weighted gather accumulate
    k_attn_out<<<N_ / 4, 256, 0, stream>>>(qf, bufA, srcOf, rowAbs, W1, b1, W2, b2, out);

    // out = relu(bn(out)) + x
    k_bnstats96<<<512, 192, 0, stream>>>(out, stats + 5 * 192);
    k_bnapply<96, 2, 0><<<eb96, 256, 0, stream>>>(out, stats + 5 * 192, g_out, b_out, x, nullptr);
}

// Round 4
// 1300.013 us; speedup vs baseline: 4.3645x; 1.1869x over previous
//
#include <hip/hip_runtime.h>
#include <math.h>

#define N_  100000
#define P_  96
#define V_  4
#define M_  70000
#define K_  43
#define KC_ 27

typedef unsigned short u16;
typedef __attribute__((ext_vector_type(8))) short bf16x8;
typedef __attribute__((ext_vector_type(4))) float f32x4;

__device__ __forceinline__ u16 f2bf(float f) {
    unsigned int u = __float_as_uint(f);
    u += 0x7fffu + ((u >> 16) & 1u);   // round-to-nearest-even
    return (u16)(u >> 16);
}
__device__ __forceinline__ float bf2f(u16 h) {
    return __uint_as_float(((unsigned int)h) << 16);
}

// ---------------------------------------------------------------------------
// srcOf[k][dst] = src  (dst unique within each map -> no collisions)
__global__ __launch_bounds__(256) void k_build_srcof(const int* __restrict__ km,
                                                     int* __restrict__ srcOf) {
    int idx = blockIdx.x * 256 + threadIdx.x;
    if (idx >= K_ * M_) return;
    int k = idx / M_;
    int e = idx - k * M_;
    const int* p = km + (size_t)(k * M_ + e) * 2;
    srcOf[(size_t)k * N_ + p[1]] = p[0];
}

// rowAbs[r] = sum_j |x[r][j]|
__global__ __launch_bounds__(256) void k_rowabs(const float* __restrict__ x,
                                                float* __restrict__ rowAbs) {
    int row = blockIdx.x * 4 + (threadIdx.x >> 6);
    int lane = threadIdx.x & 63;
    if (row >= N_) return;
    const float* xr = x + (size_t)row * 96;
    float s = 0.f;
    for (int j = lane; j < 96; j += 64) s += fabsf(xr[j]);
#pragma unroll
    for (int o = 32; o > 0; o >>= 1) s += __shfl_down(s, o, 64);
    if (lane == 0) rowAbs[row] = s;
}

// x (f32) -> xb (bf16)
__global__ __launch_bounds__(256) void k_cvt_bf16(const float* __restrict__ x,
                                                  u16* __restrict__ xb, int n) {
    int idx = blockIdx.x * 256 + threadIdx.x;
    if (idx < n) xb[idx] = f2bf(x[idx]);
}

// Wt[k][n][j] = bf16(W[k][j][n])   (27 x 96 x 96)
__global__ __launch_bounds__(256) void k_wt96(const float* __restrict__ W,
                                              u16* __restrict__ Wt) {
    int idx = blockIdx.x * 256 + threadIdx.x;
    if (idx >= KC_ * 96 * 96) return;
    int k = idx / 9216, rem = idx - k * 9216, n = rem / 96, j = rem - n * 96;
    Wt[idx] = f2bf(W[(size_t)k * 9216 + j * 96 + n]);
}

// Wt4[k][n][j] = bf16(W[k][j][n]) for n<4 else 0   (27 x 16 x 96)
__global__ __launch_bounds__(256) void k_wt4(const float* __restrict__ W,
                                             u16* __restrict__ Wt) {
    int idx = blockIdx.x * 256 + threadIdx.x;
    if (idx >= KC_ * 16 * 96) return;
    int k = idx / 1536, rem = idx - k * 1536, n = rem / 96, j = rem - n * 96;
    Wt[idx] = (n < 4) ? f2bf(W[(size_t)k * 384 + j * 4 + n]) : (u16)0;
}

// ---------------------------------------------------------------------------
// y[r][:] = sum_k x[srcOf[k][r]][:] @ W[k]  via bf16 MFMA. 64 rows/block.
__global__ __launch_bounds__(256) void k_conv96_mfma(
    const u16* __restrict__ xb, const u16* __restrict__ Wt,
    const int* __restrict__ srcOf, float* __restrict__ yout) {
    __shared__ u16 sA[64 * 104];   // gathered rows, stride 104 (2-way worst)
    __shared__ u16 sB[96 * 104];   // Wt[n][k]
    const int r0 = blockIdx.x * 64;
    const int t = threadIdx.x;
    const int wv = t >> 6, lane = t & 63;
    const int m = lane & 15, quad = lane >> 4;
    const int ea = t >> 2, jca = (t & 3) * 3;  // A staging: row ea, 3 chunks
    f32x4 acc[6];
#pragma unroll
    for (int i = 0; i < 6; i++) acc[i] = (f32x4){0.f, 0.f, 0.f, 0.f};

    for (int k = 0; k < KC_; k++) {
        __syncthreads();
        {   // stage A: 64 rows x 96 bf16, gathered
            int r = r0 + ea;
            int src = (r < N_) ? srcOf[(size_t)k * N_ + r] : -1;
            if (src >= 0) {
                const uint4* sp = (const uint4*)(xb + (size_t)src * 96);
#pragma unroll
                for (int i = 0; i < 3; i++)
                    *(uint4*)(sA + ea * 104 + (jca + i) * 8) = sp[jca + i];
            } else {
                uint4 z = make_uint4(0, 0, 0, 0);
#pragma unroll
                for (int i = 0; i < 3; i++)
                    *(uint4*)(sA + ea * 104 + (jca + i) * 8) = z;
            }
        }
        {   // stage B: 96 x 96 bf16, contiguous
            const u16* wk = Wt + (size_t)k * 9216;
#pragma unroll
            for (int i = 0; i < 5; i++) {
                int c = t + 256 * i;
                if (c < 1152) {
                    int n = c / 12, jc = c - n * 12;
                    *(uint4*)(sB + n * 104 + jc * 8) =
                        *(const uint4*)(wk + n * 96 + jc * 8);
                }
            }
        }
        __syncthreads();
#pragma unroll
        for (int kk = 0; kk < 3; kk++) {
            bf16x8 af = *(const bf16x8*)(sA + (wv * 16 + m) * 104 + kk * 32 + quad * 8);
#pragma unroll
            for (int nt = 0; nt < 6; nt++) {
                bf16x8 bfr = *(const bf16x8*)(sB + (nt * 16 + m) * 104 + kk * 32 + quad * 8);
                acc[nt] = __builtin_amdgcn_mfma_f32_16x16x32_bf16(af, bfr, acc[nt], 0, 0, 0);
            }
        }
    }
#pragma unroll
    for (int nt = 0; nt < 6; nt++) {
#pragma unroll
        for (int rg = 0; rg < 4; rg++) {
            int r = r0 + wv * 16 + quad * 4 + rg;
            if (r < N_) yout[(size_t)r * 96 + nt * 16 + m] = acc[nt][rg];
        }
    }
}

// 96->4 conv via MFMA (N padded to 16). 128 rows/block.
__global__ __launch_bounds__(256) void k_conv4_mfma(
    const u16* __restrict__ xbA, const u16* __restrict__ Wt4,
    const int* __restrict__ srcOf, float* __restrict__ qf) {
    __shared__ u16 sA[128 * 104];
    __shared__ u16 sB[16 * 104];
    const int r0 = blockIdx.x * 128;
    const int t = threadIdx.x;
    const int wv = t >> 6, lane = t & 63;
    const int m = lane & 15, quad = lane >> 4;
    const int ea = t >> 1, jca = (t & 1) * 6;
    f32x4 acc[2];
    acc[0] = (f32x4){0.f, 0.f, 0.f, 0.f};
    acc[1] = (f32x4){0.f, 0.f, 0.f, 0.f};
    for (int k = 0; k < KC_; k++) {
        __syncthreads();
        {
            int r = r0 + ea;
            int src = (r < N_) ? srcOf[(size_t)k * N_ + r] : -1;
            if (src >= 0) {
                const uint4* sp = (const uint4*)(xbA + (size_t)src * 96);
#pragma unroll
                for (int i = 0; i < 6; i++)
                    *(uint4*)(sA + ea * 104 + (jca + i) * 8) = sp[jca + i];
            } else {
                uint4 z = make_uint4(0, 0, 0, 0);
#pragma unroll
                for (int i = 0; i < 6; i++)
                    *(uint4*)(sA + ea * 104 + (jca + i) * 8) = z;
            }
        }
        if (t < 192) {
            int n = t / 12, jc = t - (t / 12) * 12;
            *(uint4*)(sB + n * 104 + jc * 8) =
                *(const uint4*)(Wt4 + (size_t)k * 1536 + n * 96 + jc * 8);
        }
        __syncthreads();
#pragma unroll
        for (int kk = 0; kk < 3; kk++) {
            bf16x8 bfr = *(const bf16x8*)(sB + m * 104 + kk * 32 + quad * 8);
#pragma unroll
            for (int rt = 0; rt < 2; rt++) {
                bf16x8 af = *(const bf16x8*)(sA + ((wv * 2 + rt) * 16 + m) * 104 + kk * 32 + quad * 8);
                acc[rt] = __builtin_amdgcn_mfma_f32_16x16x32_bf16(af, bfr, acc[rt], 0, 0, 0);
            }
        }
    }
    if (m < 4) {
#pragma unroll
        for (int rt = 0; rt < 2; rt++)
#pragma unroll
            for (int rg = 0; rg < 4; rg++) {
                int r = r0 + (wv * 2 + rt) * 16 + quad * 4 + rg;
                if (r < N_) qf[(size_t)r * 4 + m] = acc[rt][rg];
            }
    }
}

// ---------------------------------------------------------------------------
__global__ __launch_bounds__(192) void k_bnstats96(const float* __restrict__ xin,
                                                   float* __restrict__ stats) {
    __shared__ float sS[192], sQ[192];
    int t = threadIdx.x;
    int ch = t % 96, half = t / 96;
    float s = 0.f, q = 0.f;
    for (int r = blockIdx.x * 2 + half; r < N_; r += gridDim.x * 2) {
        float v = xin[(size_t)r * 96 + ch];
        s += v; q += v * v;
    }
    sS[t] = s; sQ[t] = q;
    __syncthreads();
    if (t < 96) {
        atomicAdd(&stats[ch], sS[t] + sS[t + 96]);
        atomicAdd(&stats[96 + ch], sQ[t] + sQ[t + 96]);
    }
}

__global__ __launch_bounds__(256) void k_bnstats4(const float* __restrict__ xin,
                                                  float* __restrict__ stats) {
    __shared__ float sS[256], sQ[256];
    int t = threadIdx.x;
    int c = t & 3, sub = t >> 2;
    float s = 0.f, q = 0.f;
    for (int r = blockIdx.x * 64 + sub; r < N_; r += gridDim.x * 64) {
        float v = xin[(size_t)r * 4 + c];
        s += v; q += v * v;
    }
    sS[t] = s; sQ[t] = q;
    __syncthreads();
    for (int off = 128; off >= 4; off >>= 1) {
        if (t < off) { sS[t] += sS[t + off]; sQ[t] += sQ[t + off]; }
        __syncthreads();
    }
    if (t < 4) {
        atomicAdd(&stats[t], sS[t]);
        atomicAdd(&stats[96 + t], sQ[t]);
    }
}

// MODE 0: relu(bn)  MODE 1: relu(bn)+pe_repeat  MODE 2: relu(bn)+aux
template <int C, int MODE, int BF16OUT>
__global__ __launch_bounds__(256) void k_bnapply(float* __restrict__ y,
                                                 const float* __restrict__ stats,
                                                 const float* __restrict__ g,
                                                 const float* __restrict__ b,
                                                 const float* __restrict__ aux,
                                                 u16* __restrict__ ybf) {
    int idx = blockIdx.x * 256 + threadIdx.x;
    if (idx >= N_ * C) return;
    int ch = idx % C;
    float mean = stats[ch] * (1.f / N_);
    float var = stats[96 + ch] * (1.f / N_) - mean * mean;
    float scale = g[ch] * rsqrtf(fmaxf(var, 0.f) + 1e-5f);
    float v = (y[idx] - mean) * scale + b[ch];
    v = fmaxf(v, 0.f);
    if (MODE == 1) { int r = idx / C; v += aux[(size_t)r * 4 + (ch / 24)]; }
    if (MODE == 2) { v += aux[idx]; }
    y[idx] = v;
    if (BF16OUT) ybf[idx] = f2bf(v);
}

__global__ __launch_bounds__(256) void k_pe1(const float* __restrict__ coords,
                                             const float* __restrict__ Wp1,
                                             float* __restrict__ out) {
    int idx = blockIdx.x * 256 + threadIdx.x;
    if (idx >= N_ * 96) return;
    int r = idx / 96, ch = idx - r * 96;
    float c0 = coords[r * 3], c1 = coords[r * 3 + 1], c2 = coords[r * 3 + 2];
    out[idx] = c0 * Wp1[ch] + c1 * Wp1[96 + ch] + c2 * Wp1[192 + ch];
}

__global__ __launch_bounds__(256) void k_pe2(const float* __restrict__ hin,
                                             const float* __restrict__ Wp2,
                                             float* __restrict__ out) {
    int idx = blockIdx.x * 256 + threadIdx.x;
    if (idx >= N_ * 4) return;
    int r = idx / 4, c = idx & 3;
    const float* hr = hin + (size_t)r * 96;
    float acc = 0.f;
#pragma unroll 4
    for (int j = 0; j < 96; j++) acc += hr[j] * Wp2[j * 4 + c];
    out[idx] = acc;
}

// ---------------------------------------------------------------------------
// Phase A: per-row logits (43x4) -> softmax -> final bf16 weights wb[r][44][4]
// wb[r][k][c] = mask_k * softmax(logits)[ATTN_IDX[k]][c]
__global__ __launch_bounds__(256) void k_attn_logits(
    const float* __restrict__ qf, const int* __restrict__ srcOf,
    const float* __restrict__ rowAbs,
    const float* __restrict__ W1, const float* __restrict__ b1,
    const float* __restrict__ W2, const float* __restrict__ b2,
    u16* __restrict__ wb) {
    const int t = threadIdx.x;
    const int wv = t >> 6, lane = t & 63;
    const int r = blockIdx.x * 4 + wv;   // N_ % 4 == 0
    __shared__ float sW1t[384], sW2[384], sb1[96], sb2[4];
    __shared__ float slog[4][K_][V_];
    __shared__ float sa[4][K_][V_];

    for (int p = t; p < 384; p += 256) {
        sW1t[p] = W1[(p & 3) * 96 + (p >> 2)];
        sW2[p] = W2[p];
    }
    if (t < 96) sb1[t] = b1[t];
    if (t < 4) sb2[t] = b2[t];

    float4 qr = *(const float4*)(qf + (size_t)r * 4);
    int s = -1;
    float mk = 0.f;
    if (lane < K_) {
        s = srcOf[(size_t)lane * N_ + r];
        mk = (s >= 0 && rowAbs[s] > 0.f) ? 1.f : 0.f;
    }
    float4 qs = *(const float4*)(qf + (size_t)(s >= 0 ? s : 0) * 4);
    float d0 = (qs.x - qr.x) * mk, d1 = (qs.y - qr.y) * mk;
    float d2 = (qs.z - qr.z) * mk, d3 = (qs.w - qr.w) * mk;
    __syncthreads();

    float l0 = 0.f, l1 = 0.f, l2 = 0.f, l3 = 0.f;
#pragma unroll 4
    for (int j = 0; j < 96; j++) {
        float4 w1 = *(const float4*)&sW1t[j * 4];
        float h = sb1[j] + d0 * w1.x + d1 * w1.y + d2 * w1.z + d3 * w1.w;
        h = fmaxf(h, 0.f);
        float4 w2 = *(const float4*)&sW2[j * 4];
        l0 += h * w2.x; l1 += h * w2.y; l2 += h * w2.z; l3 += h * w2.w;
    }
    if (lane < K_) {
        slog[wv][lane][0] = (l0 + sb2[0]) * mk;
        slog[wv][lane][1] = (l1 + sb2[1]) * mk;
        slog[wv][lane][2] = (l2 + sb2[2]) * mk;
        slog[wv][lane][3] = (l3 + sb2[3]) * mk;
    }
    __syncthreads();

    if (lane < 4) {  // softmax over all 43 (uncovered contribute exp(0))
        float mx = 0.f;
        for (int k = 0; k < K_; k++) mx = fmaxf(mx, slog[wv][k][lane]);
        float den = 0.f;
        for (int k = 0; k < K_; k++) den += __expf(slog[wv][k][lane] - mx);
        float inv = 1.f / den;
        for (int k = 0; k < K_; k++)
            sa[wv][k][lane] = __expf(slog[wv][k][lane] - mx) * inv;
    }
    __syncthreads();

    if (lane < K_) {
        int idxk = (lane < 27) ? lane : ((lane < 35) ? (lane - 27) : (lane - 35));
        ushort4 wout;
        wout.x = f2bf(mk * sa[wv][idxk][0]);
        wout.y = f2bf(mk * sa[wv][idxk][1]);
        wout.z = f2bf(mk * sa[wv][idxk][2]);
        wout.w = f2bf(mk * sa[wv][idxk][3]);
        *(ushort4*)(wb + ((size_t)r * 44 + lane) * 4) = wout;
    }
}

// Phase B: out[r][ch] = sum_k wb[r][k][cg] * vfb[src_k[r]][ch]
// thread = (r, c4): 24 threads stream one vf row; branchless clamp (row 0 L1-hot).
__global__ __launch_bounds__(256) void k_attn_gather(
    const u16* __restrict__ vfb, const u16* __restrict__ wb,
    const int* __restrict__ srcOf, float* __restrict__ out) {
    int idx = blockIdx.x * 256 + threadIdx.x;
    int r = idx / 24, c4 = idx - r * 24;
    if (r >= N_) return;
    int cg = c4 / 6;
    const u16* wrow = wb + (size_t)r * 176 + cg;
    float a0 = 0.f, a1 = 0.f, a2 = 0.f, a3 = 0.f;
    for (int k = 0; k < K_; k++) {
        int s = srcOf[(size_t)k * N_ + r];
        float w = bf2f(wrow[(size_t)k * 4]);
        w = (s >= 0) ? w : 0.f;
        int sc = (s >= 0) ? s : 0;
        ushort4 v = *(const ushort4*)(vfb + (size_t)sc * 96 + c4 * 4);
        a0 += w * bf2f(v.x);
        a1 += w * bf2f(v.y);
        a2 += w * bf2f(v.z);
        a3 += w * bf2f(v.w);
    }
    float4 o = make_float4(a0, a1, a2, a3);
    *(float4*)(out + (size_t)r * 96 + c4 * 4) = o;
}

// ---------------------------------------------------------------------------
extern "C" void kernel_launch(void* const* d_in, const int* in_sizes, int n_in,
                              void* d_out, int out_size, void* d_ws, size_t ws_size,
                              hipStream_t stream) {
    const float* x      = (const float*)d_in[0];
    const float* coords = (const float*)d_in[1];
    const float* Wq1 = (const float*)d_in[2];
    const float* gq1 = (const float*)d_in[3];
    const float* bq1 = (const float*)d_in[4];
    const float* Wq2 = (const float*)d_in[5];
    const float* gq2 = (const float*)d_in[6];
    const float* bq2 = (const float*)d_in[7];
    const float* Wv  = (const float*)d_in[8];
    const float* gv  = (const float*)d_in[9];
    const float* bv  = (const float*)d_in[10];
    const float* Wp1 = (const float*)d_in[11];
    const float* gp1 = (const float*)d_in[12];
    const float* bp1 = (const float*)d_in[13];
    const float* Wp2 = (const float*)d_in[14];
    const float* gp2 = (const float*)d_in[15];
    const float* bp2 = (const float*)d_in[16];
    const float* W1  = (const float*)d_in[17];
    const float* b1  = (const float*)d_in[18];
    const float* W2  = (const float*)d_in[19];
    const float* b2  = (const float*)d_in[20];
    const float* g_out = (const float*)d_in[21];
    const float* b_out = (const float*)d_in[22];
    const int* kmaps = (const int*)d_in[23];
    float* out = (float*)d_out;

    char* ws = (char*)d_ws;
    int*   srcOf  = (int*)ws;                        //  0          + 17,200,000
    float* rowAbs = (float*)(ws + 17200000);         //             +    400,000
    float* bufA   = (float*)(ws + 17600000);         //             + 38,400,000
    u16*   wbuf   = (u16*)(ws + 17600000);           // overlays bufA (after last read): 35,200,000
    u16*   bufAb  = (u16*)(ws + 56000000);           //             + 19,200,000
    u16*   xb     = (u16*)(ws + 75200000);           //             + 19,200,000
    u16*   vfb    = (u16*)(ws + 75200000);           // overlays xb (after last read): 19,200,000
    float* qf     = (float*)(ws + 94400000);         //             +  1,600,000
    float* peb    = (float*)(ws + 96000000);         //             +  1,600,000
    u16*   Wq1t   = (u16*)(ws + 97600000);           //             +    497,664
    u16*   Wvt    = (u16*)(ws + 98097664);           //             +    497,664
    u16*   Wq2t   = (u16*)(ws + 98595328);           //             +     82,944
    float* stats  = (float*)(ws + 98678272);         //             +      4,608

    hipMemsetAsync(srcOf, 0xFF, (size_t)K_ * N_ * 4, stream);  // -1
    hipMemsetAsync(stats, 0, 6 * 192 * 4, stream);

    k_build_srcof<<<(K_ * M_ + 255) / 256, 256, 0, stream>>>(kmaps, srcOf);
    k_rowabs<<<N_ / 4, 256, 0, stream>>>(x, rowAbs);
    k_cvt_bf16<<<N_ * 96 / 256, 256, 0, stream>>>(x, xb, N_ * 96);
    k_wt96<<<(KC_ * 9216 + 255) / 256, 256, 0, stream>>>(Wq1, Wq1t);
    k_wt96<<<(KC_ * 9216 + 255) / 256, 256, 0, stream>>>(Wv, Wvt);
    k_wt4<<<(KC_ * 1536 + 255) / 256, 256, 0, stream>>>(Wq2, Wq2t);

    const int cb96 = (N_ + 63) / 64;     // 1563
    const int cb4  = (N_ + 127) / 128;   // 782
    const int eb96 = N_ * 96 / 256;      // 37500
    const int eb4  = (N_ * 4 + 255) / 256;

    // qf = cbr(cbr(x, Wq1), Wq2)
    k_conv96_mfma<<<cb96, 256, 0, stream>>>(xb, Wq1t, srcOf, bufA);
    k_bnstats96<<<512, 192, 0, stream>>>(bufA, stats + 0 * 192);
    k_bnapply<96, 0, 1><<<eb96, 256, 0, stream>>>(bufA, stats + 0 * 192, gq1, bq1, nullptr, bufAb);
    k_conv4_mfma<<<cb4, 256, 0, stream>>>(bufAb, Wq2t, srcOf, qf);
    k_bnstats4<<<512, 256, 0, stream>>>(qf, stats + 1 * 192);
    k_bnapply<4, 0, 0><<<eb4, 256, 0, stream>>>(qf, stats + 1 * 192, gq2, bq2, nullptr, nullptr);

    // pe chain (bufA reused as scratch; conv4 already consumed bufAb)
    k_pe1<<<eb96, 256, 0, stream>>>(coords, Wp1, bufA);
    k_bnstats96<<<512, 192, 0, stream>>>(bufA, stats + 2 * 192);
    k_bnapply<96, 0, 0><<<eb96, 256, 0, stream>>>(bufA, stats + 2 * 192, gp1, bp1, nullptr, nullptr);
    k_pe2<<<eb4, 256, 0, stream>>>(bufA, Wp2, peb);
    k_bnstats4<<<512, 256, 0, stream>>>(peb, stats + 3 * 192);
    k_bnapply<4, 0, 0><<<eb4, 256, 0, stream>>>(peb, stats + 3 * 192, gp2, bp2, nullptr, nullptr);

    // v_f = cbr(x, Wv) + repeat(pe, 24)  -> bufA (f32) + vfb (bf16, overlays xb)
    k_conv96_mfma<<<cb96, 256, 0, stream>>>(xb, Wvt, srcOf, bufA);
    k_bnstats96<<<512, 192, 0, stream>>>(bufA, stats + 4 * 192);
    k_bnapply<96, 1, 1><<<eb96, 256, 0, stream>>>(bufA, stats + 4 * 192, gv, bv, peb, vfb);

    // attention: logits+softmax -> bf16 weights (wbuf overlays bufA), then gather
    k_attn_logits<<<N_ / 4, 256, 0, stream>>>(qf, srcOf, rowAbs, W1, b1, W2, b2, wbuf);
    k_attn_gather<<<(N_ * 24) / 256, 256, 0, stream>>>(vfb, wbuf, srcOf, out);

    // out = relu(bn(out)) + x
    k_bnstats96<<<512, 192, 0, stream>>>(out, stats + 5 * 192);
    k_bnapply<96, 2, 0><<<eb96, 256, 0, stream>>>(out, stats + 5 * 192, g_out, b_out, x, nullptr);
}

// Round 5
// 1201.783 us; speedup vs baseline: 4.7212x; 1.0817x over previous
//
#include <hip/hip_runtime.h>
#include <math.h>

#define N_  100000
#define P_  96
#define V_  4
#define M_  70000
#define K_  43
#define KC_ 27

typedef unsigned short u16;
typedef __attribute__((ext_vector_type(8))) short bf16x8;
typedef __attribute__((ext_vector_type(4))) float f32x4;

__device__ __forceinline__ u16 f2bf(float f) {
    unsigned int u = __float_as_uint(f);
    u += 0x7fffu + ((u >> 16) & 1u);   // round-to-nearest-even
    return (u16)(u >> 16);
}
__device__ __forceinline__ float bf2f(u16 h) {
    return __uint_as_float(((unsigned int)h) << 16);
}

// ---------------------------------------------------------------------------
// srcOf[k][dst] = src  (dst unique within each map -> no collisions)
__global__ __launch_bounds__(256) void k_build_srcof(const int* __restrict__ km,
                                                     int* __restrict__ srcOf) {
    int idx = blockIdx.x * 256 + threadIdx.x;
    if (idx >= K_ * M_) return;
    int k = idx / M_;
    int e = idx - k * M_;
    const int* p = km + (size_t)(k * M_ + e) * 2;
    srcOf[(size_t)k * N_ + p[1]] = p[0];
}

// rowAbs[r] = sum_j |x[r][j]|
__global__ __launch_bounds__(256) void k_rowabs(const float* __restrict__ x,
                                                float* __restrict__ rowAbs) {
    int row = blockIdx.x * 4 + (threadIdx.x >> 6);
    int lane = threadIdx.x & 63;
    if (row >= N_) return;
    const float* xr = x + (size_t)row * 96;
    float s = 0.f;
    for (int j = lane; j < 96; j += 64) s += fabsf(xr[j]);
#pragma unroll
    for (int o = 32; o > 0; o >>= 1) s += __shfl_down(s, o, 64);
    if (lane == 0) rowAbs[row] = s;
}

// x (f32) -> xb (bf16)
__global__ __launch_bounds__(256) void k_cvt_bf16(const float* __restrict__ x,
                                                  u16* __restrict__ xb, int n) {
    int idx = blockIdx.x * 256 + threadIdx.x;
    if (idx < n) xb[idx] = f2bf(x[idx]);
}

// Wt[k][n][j] = bf16(W[k][j][n])   (27 x 96 x 96)
__global__ __launch_bounds__(256) void k_wt96(const float* __restrict__ W,
                                              u16* __restrict__ Wt) {
    int idx = blockIdx.x * 256 + threadIdx.x;
    if (idx >= KC_ * 96 * 96) return;
    int k = idx / 9216, rem = idx - k * 9216, n = rem / 96, j = rem - n * 96;
    Wt[idx] = f2bf(W[(size_t)k * 9216 + j * 96 + n]);
}

// Wt4[k][n][j] = bf16(W[k][j][n]) for n<4 else 0   (27 x 16 x 96)
__global__ __launch_bounds__(256) void k_wt4(const float* __restrict__ W,
                                             u16* __restrict__ Wt) {
    int idx = blockIdx.x * 256 + threadIdx.x;
    if (idx >= KC_ * 16 * 96) return;
    int k = idx / 1536, rem = idx - k * 1536, n = rem / 96, j = rem - n * 96;
    Wt[idx] = (n < 4) ? f2bf(W[(size_t)k * 384 + j * 4 + n]) : (u16)0;
}

// w1b[j][c32] = bf16(W1[c][j]) c<4 else 0 (96x32); w2b[n16][j] = bf16(W2[j][n]) n<4 else 0 (16x96)
__global__ __launch_bounds__(256) void k_w12b(const float* __restrict__ W1,
                                              const float* __restrict__ W2,
                                              u16* __restrict__ w1b,
                                              u16* __restrict__ w2b) {
    int t = blockIdx.x * 256 + threadIdx.x;
    if (t < 96 * 32) {
        int j = t >> 5, c = t & 31;
        w1b[t] = (c < 4) ? f2bf(W1[c * 96 + j]) : (u16)0;
    }
    if (t < 16 * 96) {
        int n = t / 96, j = t - n * 96;
        w2b[t] = (n < 4) ? f2bf(W2[j * 4 + n]) : (u16)0;
    }
}

// ---------------------------------------------------------------------------
// y[r][:] = sum_k x[srcOf[k][r]][:] @ W[k]  via bf16 MFMA. 64 rows/block.
__global__ __launch_bounds__(256) void k_conv96_mfma(
    const u16* __restrict__ xb, const u16* __restrict__ Wt,
    const int* __restrict__ srcOf, float* __restrict__ yout) {
    __shared__ u16 sA[64 * 104];   // gathered rows, stride 104 (2-way worst)
    __shared__ u16 sB[96 * 104];   // Wt[n][k]
    const int r0 = blockIdx.x * 64;
    const int t = threadIdx.x;
    const int wv = t >> 6, lane = t & 63;
    const int m = lane & 15, quad = lane >> 4;
    const int ea = t >> 2, jca = (t & 3) * 3;  // A staging: row ea, 3 chunks
    f32x4 acc[6];
#pragma unroll
    for (int i = 0; i < 6; i++) acc[i] = (f32x4){0.f, 0.f, 0.f, 0.f};

    for (int k = 0; k < KC_; k++) {
        __syncthreads();
        {   // stage A: 64 rows x 96 bf16, gathered
            int r = r0 + ea;
            int src = (r < N_) ? srcOf[(size_t)k * N_ + r] : -1;
            if (src >= 0) {
                const uint4* sp = (const uint4*)(xb + (size_t)src * 96);
#pragma unroll
                for (int i = 0; i < 3; i++)
                    *(uint4*)(sA + ea * 104 + (jca + i) * 8) = sp[jca + i];
            } else {
                uint4 z = make_uint4(0, 0, 0, 0);
#pragma unroll
                for (int i = 0; i < 3; i++)
                    *(uint4*)(sA + ea * 104 + (jca + i) * 8) = z;
            }
        }
        {   // stage B: 96 x 96 bf16, contiguous
            const u16* wk = Wt + (size_t)k * 9216;
#pragma unroll
            for (int i = 0; i < 5; i++) {
                int c = t + 256 * i;
                if (c < 1152) {
                    int n = c / 12, jc = c - n * 12;
                    *(uint4*)(sB + n * 104 + jc * 8) =
                        *(const uint4*)(wk + n * 96 + jc * 8);
                }
            }
        }
        __syncthreads();
#pragma unroll
        for (int kk = 0; kk < 3; kk++) {
            bf16x8 af = *(const bf16x8*)(sA + (wv * 16 + m) * 104 + kk * 32 + quad * 8);
#pragma unroll
            for (int nt = 0; nt < 6; nt++) {
                bf16x8 bfr = *(const bf16x8*)(sB + (nt * 16 + m) * 104 + kk * 32 + quad * 8);
                acc[nt] = __builtin_amdgcn_mfma_f32_16x16x32_bf16(af, bfr, acc[nt], 0, 0, 0);
            }
        }
    }
#pragma unroll
    for (int nt = 0; nt < 6; nt++) {
#pragma unroll
        for (int rg = 0; rg < 4; rg++) {
            int r = r0 + wv * 16 + quad * 4 + rg;
            if (r < N_) yout[(size_t)r * 96 + nt * 16 + m] = acc[nt][rg];
        }
    }
}

// 96->4 conv via MFMA (N padded to 16). 128 rows/block.
__global__ __launch_bounds__(256) void k_conv4_mfma(
    const u16* __restrict__ xbA, const u16* __restrict__ Wt4,
    const int* __restrict__ srcOf, float* __restrict__ qf) {
    __shared__ u16 sA[128 * 104];
    __shared__ u16 sB[16 * 104];
    const int r0 = blockIdx.x * 128;
    const int t = threadIdx.x;
    const int wv = t >> 6, lane = t & 63;
    const int m = lane & 15, quad = lane >> 4;
    const int ea = t >> 1, jca = (t & 1) * 6;
    f32x4 acc[2];
    acc[0] = (f32x4){0.f, 0.f, 0.f, 0.f};
    acc[1] = (f32x4){0.f, 0.f, 0.f, 0.f};
    for (int k = 0; k < KC_; k++) {
        __syncthreads();
        {
            int r = r0 + ea;
            int src = (r < N_) ? srcOf[(size_t)k * N_ + r] : -1;
            if (src >= 0) {
                const uint4* sp = (const uint4*)(xbA + (size_t)src * 96);
#pragma unroll
                for (int i = 0; i < 6; i++)
                    *(uint4*)(sA + ea * 104 + (jca + i) * 8) = sp[jca + i];
            } else {
                uint4 z = make_uint4(0, 0, 0, 0);
#pragma unroll
                for (int i = 0; i < 6; i++)
                    *(uint4*)(sA + ea * 104 + (jca + i) * 8) = z;
            }
        }
        if (t < 192) {
            int n = t / 12, jc = t - (t / 12) * 12;
            *(uint4*)(sB + n * 104 + jc * 8) =
                *(const uint4*)(Wt4 + (size_t)k * 1536 + n * 96 + jc * 8);
        }
        __syncthreads();
#pragma unroll
        for (int kk = 0; kk < 3; kk++) {
            bf16x8 bfr = *(const bf16x8*)(sB + m * 104 + kk * 32 + quad * 8);
#pragma unroll
            for (int rt = 0; rt < 2; rt++) {
                bf16x8 af = *(const bf16x8*)(sA + ((wv * 2 + rt) * 16 + m) * 104 + kk * 32 + quad * 8);
                acc[rt] = __builtin_amdgcn_mfma_f32_16x16x32_bf16(af, bfr, acc[rt], 0, 0, 0);
            }
        }
    }
    if (m < 4) {
#pragma unroll
        for (int rt = 0; rt < 2; rt++)
#pragma unroll
            for (int rg = 0; rg < 4; rg++) {
                int r = r0 + (wv * 2 + rt) * 16 + quad * 4 + rg;
                if (r < N_) qf[(size_t)r * 4 + m] = acc[rt][rg];
            }
    }
}

// ---------------------------------------------------------------------------
__global__ __launch_bounds__(192) void k_bnstats96(const float* __restrict__ xin,
                                                   float* __restrict__ stats) {
    __shared__ float sS[192], sQ[192];
    int t = threadIdx.x;
    int ch = t % 96, half = t / 96;
    float s = 0.f, q = 0.f;
    for (int r = blockIdx.x * 2 + half; r < N_; r += gridDim.x * 2) {
        float v = xin[(size_t)r * 96 + ch];
        s += v; q += v * v;
    }
    sS[t] = s; sQ[t] = q;
    __syncthreads();
    if (t < 96) {
        atomicAdd(&stats[ch], sS[t] + sS[t + 96]);
        atomicAdd(&stats[96 + ch], sQ[t] + sQ[t + 96]);
    }
}

__global__ __launch_bounds__(256) void k_bnstats4(const float* __restrict__ xin,
                                                  float* __restrict__ stats) {
    __shared__ float sS[256], sQ[256];
    int t = threadIdx.x;
    int c = t & 3, sub = t >> 2;
    float s = 0.f, q = 0.f;
    for (int r = blockIdx.x * 64 + sub; r < N_; r += gridDim.x * 64) {
        float v = xin[(size_t)r * 4 + c];
        s += v; q += v * v;
    }
    sS[t] = s; sQ[t] = q;
    __syncthreads();
    for (int off = 128; off >= 4; off >>= 1) {
        if (t < off) { sS[t] += sS[t + off]; sQ[t] += sQ[t + off]; }
        __syncthreads();
    }
    if (t < 4) {
        atomicAdd(&stats[t], sS[t]);
        atomicAdd(&stats[96 + t], sQ[t]);
    }
}

// MODE 0: relu(bn)  MODE 1: relu(bn)+pe_repeat  MODE 2: relu(bn)+aux
template <int C, int MODE, int BF16OUT>
__global__ __launch_bounds__(256) void k_bnapply(float* __restrict__ y,
                                                 const float* __restrict__ stats,
                                                 const float* __restrict__ g,
                                                 const float* __restrict__ b,
                                                 const float* __restrict__ aux,
                                                 u16* __restrict__ ybf) {
    int idx = blockIdx.x * 256 + threadIdx.x;
    if (idx >= N_ * C) return;
    int ch = idx % C;
    float mean = stats[ch] * (1.f / N_);
    float var = stats[96 + ch] * (1.f / N_) - mean * mean;
    float scale = g[ch] * rsqrtf(fmaxf(var, 0.f) + 1e-5f);
    float v = (y[idx] - mean) * scale + b[ch];
    v = fmaxf(v, 0.f);
    if (MODE == 1) { int r = idx / C; v += aux[(size_t)r * 4 + (ch / 24)]; }
    if (MODE == 2) { v += aux[idx]; }
    y[idx] = v;
    if (BF16OUT) ybf[idx] = f2bf(v);
}

__global__ __launch_bounds__(256) void k_pe1(const float* __restrict__ coords,
                                             const float* __restrict__ Wp1,
                                             float* __restrict__ out) {
    int idx = blockIdx.x * 256 + threadIdx.x;
    if (idx >= N_ * 96) return;
    int r = idx / 96, ch = idx - r * 96;
    float c0 = coords[r * 3], c1 = coords[r * 3 + 1], c2 = coords[r * 3 + 2];
    out[idx] = c0 * Wp1[ch] + c1 * Wp1[96 + ch] + c2 * Wp1[192 + ch];
}

__global__ __launch_bounds__(256) void k_pe2(const float* __restrict__ hin,
                                             const float* __restrict__ Wp2,
                                             float* __restrict__ out) {
    int idx = blockIdx.x * 256 + threadIdx.x;
    if (idx >= N_ * 4) return;
    int r = idx / 4, c = idx & 3;
    const float* hr = hin + (size_t)r * 96;
    float acc = 0.f;
#pragma unroll 4
    for (int j = 0; j < 96; j++) acc += hr[j] * Wp2[j * 4 + c];
    out[idx] = acc;
}

// ---------------------------------------------------------------------------
// MFMA attention logits: 32 rows/block, pairs P = rL*44+k, 88 M-tiles of 16.
// GEMM1: d(16x32,K-pad) @ W1(32x96) -> relu -> LDS transpose -> GEMM2 @ W2(96x16-pad)
// -> masked logits in LDS -> softmax over k -> bf16 weights wb[r][44][4].
__global__ __launch_bounds__(256) void k_attn_logits_mfma(
    const float* __restrict__ qf, const int* __restrict__ srcOf,
    const float* __restrict__ rowAbs,
    const u16* __restrict__ w1b, const float* __restrict__ b1,
    const u16* __restrict__ w2b, const float* __restrict__ b2,
    u16* __restrict__ wb) {
    __shared__ u16 hbuf[4][16 * 104];
    __shared__ float slog[32][44][4];
    __shared__ float smk[32][44];
    const int t = threadIdx.x;
    const int wv = t >> 6, lane = t & 63;
    const int col = lane & 15, quad = lane >> 4;
    const int r0 = blockIdx.x * 32;   // N_ % 32 == 0

    // preload B-frags (registers, reused by all 22 tiles)
    bf16x8 w1f[6];
    float b1v[6];
#pragma unroll
    for (int nt = 0; nt < 6; nt++) {
        w1f[nt] = *(const bf16x8*)(w1b + (nt * 16 + col) * 32 + quad * 8);
        b1v[nt] = b1[nt * 16 + col];
    }
    bf16x8 w2f[3];
#pragma unroll
    for (int kk = 0; kk < 3; kk++)
        w2f[kk] = *(const bf16x8*)(w2b + col * 96 + kk * 32 + quad * 8);
    float b2v = b2[col & 3];

    u16* hb = hbuf[wv];
    for (int tt = 0; tt < 22; tt++) {
        int tileBase = (wv * 22 + tt) * 16;
        // --- A-frag: d = (qf[src]-qf[r])*mask in k=0..3, zeros elsewhere
        bf16x8 af = (bf16x8){0, 0, 0, 0, 0, 0, 0, 0};
        if (quad == 0) {
            int P = tileBase + col;
            int rL = P / 44, k = P - rL * 44;
            int kc = (k < 43) ? k : 42;
            int r = r0 + rL;
            int s = srcOf[(size_t)kc * N_ + r];
            if (k == 43) s = -1;
            int sc = (s >= 0) ? s : 0;
            float mk = (s >= 0 && rowAbs[sc] > 0.f) ? 1.f : 0.f;
            float4 qs = *(const float4*)(qf + (size_t)sc * 4);
            float4 qr = *(const float4*)(qf + (size_t)r * 4);
            af[0] = (short)f2bf((qs.x - qr.x) * mk);
            af[1] = (short)f2bf((qs.y - qr.y) * mk);
            af[2] = (short)f2bf((qs.z - qr.z) * mk);
            af[3] = (short)f2bf((qs.w - qr.w) * mk);
            smk[rL][k] = mk;
        }
        // --- GEMM1: h (16 pairs x 96)
        f32x4 c1[6];
#pragma unroll
        for (int nt = 0; nt < 6; nt++) {
            c1[nt] = (f32x4){0.f, 0.f, 0.f, 0.f};
            c1[nt] = __builtin_amdgcn_mfma_f32_16x16x32_bf16(af, w1f[nt], c1[nt], 0, 0, 0);
        }
        // bias + relu, store h to LDS in [pair][j] layout (bf16)
#pragma unroll
        for (int nt = 0; nt < 6; nt++) {
#pragma unroll
            for (int rg = 0; rg < 4; rg++) {
                float h = fmaxf(c1[nt][rg] + b1v[nt], 0.f);
                hb[(quad * 4 + rg) * 104 + nt * 16 + col] = f2bf(h);
            }
        }
        // --- GEMM2: logits (16 pairs x 16(pad from 4)), K=96
        f32x4 acc2 = (f32x4){0.f, 0.f, 0.f, 0.f};
#pragma unroll
        for (int kk = 0; kk < 3; kk++) {
            bf16x8 a2 = *(const bf16x8*)(hb + col * 104 + kk * 32 + quad * 8);
            acc2 = __builtin_amdgcn_mfma_f32_16x16x32_bf16(a2, w2f[kk], acc2, 0, 0, 0);
        }
        // --- masked logits into LDS
        if (col < 4) {
#pragma unroll
            for (int rg = 0; rg < 4; rg++) {
                int P = tileBase + quad * 4 + rg;
                int rL = P / 44, k = P - rL * 44;
                if (k < 43)
                    slog[rL][k][col] = (acc2[rg] + b2v) * smk[rL][k];
            }
        }
    }
    __syncthreads();

    // softmax over k (incl. uncovered zero logits), in place
    if (t < 128) {
        int rL = t >> 2, c = t & 3;
        float mx = 0.f;
        for (int k = 0; k < K_; k++) mx = fmaxf(mx, slog[rL][k][c]);
        float den = 0.f;
        for (int k = 0; k < K_; k++) den += __expf(slog[rL][k][c] - mx);
        float inv = 1.f / den;
        for (int k = 0; k < K_; k++)
            slog[rL][k][c] = __expf(slog[rL][k][c] - mx) * inv;
    }
    __syncthreads();

    // wb[r][k][c] = mask * softmax[ATTN_IDX[k]][c]  (bf16)
    for (int p = t; p < 32 * 43; p += 256) {
        int rL = p / 43, k = p - rL * 43;
        int idxk = (k < 27) ? k : ((k < 35) ? (k - 27) : (k - 35));
        float mk = smk[rL][k];
        ushort4 wout;
        wout.x = f2bf(mk * slog[rL][idxk][0]);
        wout.y = f2bf(mk * slog[rL][idxk][1]);
        wout.z = f2bf(mk * slog[rL][idxk][2]);
        wout.w = f2bf(mk * slog[rL][idxk][3]);
        *(ushort4*)(wb + ((size_t)(r0 + rL) * 44 + k) * 4) = wout;
    }
}

// Phase B: out[r][ch] = sum_k wb[r][k][cg] * vfb[src_k[r]][ch]
// thread = (r, c4): 24 threads stream one vf row; branchless clamp (row 0 L1-hot).
__global__ __launch_bounds__(256) void k_attn_gather(
    const u16* __restrict__ vfb, const u16* __restrict__ wb,
    const int* __restrict__ srcOf, float* __restrict__ out) {
    int idx = blockIdx.x * 256 + threadIdx.x;
    int r = idx / 24, c4 = idx - r * 24;
    if (r >= N_) return;
    int cg = c4 / 6;
    const u16* wrow = wb + (size_t)r * 176 + cg;
    float a0 = 0.f, a1 = 0.f, a2 = 0.f, a3 = 0.f;
    for (int k = 0; k < K_; k++) {
        int s = srcOf[(size_t)k * N_ + r];
        float w = bf2f(wrow[(size_t)k * 4]);
        w = (s >= 0) ? w : 0.f;
        int sc = (s >= 0) ? s : 0;
        ushort4 v = *(const ushort4*)(vfb + (size_t)sc * 96 + c4 * 4);
        a0 += w * bf2f(v.x);
        a1 += w * bf2f(v.y);
        a2 += w * bf2f(v.z);
        a3 += w * bf2f(v.w);
    }
    float4 o = make_float4(a0, a1, a2, a3);
    *(float4*)(out + (size_t)r * 96 + c4 * 4) = o;
}

// ---------------------------------------------------------------------------
extern "C" void kernel_launch(void* const* d_in, const int* in_sizes, int n_in,
                              void* d_out, int out_size, void* d_ws, size_t ws_size,
                              hipStream_t stream) {
    const float* x      = (const float*)d_in[0];
    const float* coords = (const float*)d_in[1];
    const float* Wq1 = (const float*)d_in[2];
    const float* gq1 = (const float*)d_in[3];
    const float* bq1 = (const float*)d_in[4];
    const float* Wq2 = (const float*)d_in[5];
    const float* gq2 = (const float*)d_in[6];
    const float* bq2 = (const float*)d_in[7];
    const float* Wv  = (const float*)d_in[8];
    const float* gv  = (const float*)d_in[9];
    const float* bv  = (const float*)d_in[10];
    const float* Wp1 = (const float*)d_in[11];
    const float* gp1 = (const float*)d_in[12];
    const float* bp1 = (const float*)d_in[13];
    const float* Wp2 = (const float*)d_in[14];
    const float* gp2 = (const float*)d_in[15];
    const float* bp2 = (const float*)d_in[16];
    const float* W1  = (const float*)d_in[17];
    const float* b1  = (const float*)d_in[18];
    const float* W2  = (const float*)d_in[19];
    const float* b2  = (const float*)d_in[20];
    const float* g_out = (const float*)d_in[21];
    const float* b_out = (const float*)d_in[22];
    const int* kmaps = (const int*)d_in[23];
    float* out = (float*)d_out;

    char* ws = (char*)d_ws;
    int*   srcOf  = (int*)ws;                        //  0          + 17,200,000
    float* rowAbs = (float*)(ws + 17200000);         //             +    400,000
    float* bufA   = (float*)(ws + 17600000);         //             + 38,400,000
    u16*   wbuf   = (u16*)(ws + 17600000);           // overlays bufA (after last read): 35,200,000
    u16*   bufAb  = (u16*)(ws + 56000000);           //             + 19,200,000
    u16*   xb     = (u16*)(ws + 75200000);           //             + 19,200,000
    u16*   vfb    = (u16*)(ws + 75200000);           // overlays xb (after last read): 19,200,000
    float* qf     = (float*)(ws + 94400000);         //             +  1,600,000
    float* peb    = (float*)(ws + 96000000);         //             +  1,600,000
    u16*   Wq1t   = (u16*)(ws + 97600000);           //             +    497,664
    u16*   Wvt    = (u16*)(ws + 98097664);           //             +    497,664
    u16*   Wq2t   = (u16*)(ws + 98595328);           //             +     82,944
    u16*   w1b    = (u16*)(ws + 98678272);           //             +      6,144
    u16*   w2b    = (u16*)(ws + 98684416);           //             +      3,072
    float* stats  = (float*)(ws + 98687488);         //             +      4,608

    hipMemsetAsync(srcOf, 0xFF, (size_t)K_ * N_ * 4, stream);  // -1
    hipMemsetAsync(stats, 0, 6 * 192 * 4, stream);

    k_build_srcof<<<(K_ * M_ + 255) / 256, 256, 0, stream>>>(kmaps, srcOf);
    k_rowabs<<<N_ / 4, 256, 0, stream>>>(x, rowAbs);
    k_cvt_bf16<<<N_ * 96 / 256, 256, 0, stream>>>(x, xb, N_ * 96);
    k_wt96<<<(KC_ * 9216 + 255) / 256, 256, 0, stream>>>(Wq1, Wq1t);
    k_wt96<<<(KC_ * 9216 + 255) / 256, 256, 0, stream>>>(Wv, Wvt);
    k_wt4<<<(KC_ * 1536 + 255) / 256, 256, 0, stream>>>(Wq2, Wq2t);
    k_w12b<<<12, 256, 0, stream>>>(W1, W2, w1b, w2b);

    const int cb96 = (N_ + 63) / 64;     // 1563
    const int cb4  = (N_ + 127) / 128;   // 782
    const int eb96 = N_ * 96 / 256;      // 37500
    const int eb4  = (N_ * 4 + 255) / 256;

    // qf = cbr(cbr(x, Wq1), Wq2)
    k_conv96_mfma<<<cb96, 256, 0, stream>>>(xb, Wq1t, srcOf, bufA);
    k_bnstats96<<<512, 192, 0, stream>>>(bufA, stats + 0 * 192);
    k_bnapply<96, 0, 1><<<eb96, 256, 0, stream>>>(bufA, stats + 0 * 192, gq1, bq1, nullptr, bufAb);
    k_conv4_mfma<<<cb4, 256, 0, stream>>>(bufAb, Wq2t, srcOf, qf);
    k_bnstats4<<<512, 256, 0, stream>>>(qf, stats + 1 * 192);
    k_bnapply<4, 0, 0><<<eb4, 256, 0, stream>>>(qf, stats + 1 * 192, gq2, bq2, nullptr, nullptr);

    // pe chain (bufA reused as scratch; conv4 already consumed bufAb)
    k_pe1<<<eb96, 256, 0, stream>>>(coords, Wp1, bufA);
    k_bnstats96<<<512, 192, 0, stream>>>(bufA, stats + 2 * 192);
    k_bnapply<96, 0, 0><<<eb96, 256, 0, stream>>>(bufA, stats + 2 * 192, gp1, bp1, nullptr, nullptr);
    k_pe2<<<eb4, 256, 0, stream>>>(bufA, Wp2, peb);
    k_bnstats4<<<512, 256, 0, stream>>>(peb, stats + 3 * 192);
    k_bnapply<4, 0, 0><<<eb4, 256, 0, stream>>>(peb, stats + 3 * 192, gp2, bp2, nullptr, nullptr);

    // v_f = cbr(x, Wv) + repeat(pe, 24)  -> bufA (f32) + vfb (bf16, overlays xb)
    k_conv96_mfma<<<cb96, 256, 0, stream>>>(xb, Wvt, srcOf, bufA);
    k_bnstats96<<<512, 192, 0, stream>>>(bufA, stats + 4 * 192);
    k_bnapply<96, 1, 1><<<eb96, 256, 0, stream>>>(bufA, stats + 4 * 192, gv, bv, peb, vfb);

    // attention: MFMA logits+softmax -> bf16 weights (wbuf overlays bufA), then gather
    k_attn_logits_mfma<<<N_ / 32, 256, 0, stream>>>(qf, srcOf, rowAbs, w1b, b1, w2b, b2, wbuf);
    k_attn_gather<<<(N_ * 24) / 256, 256, 0, stream>>>(vfb, wbuf, srcOf, out);

    // out = relu(bn(out)) + x
    k_bnstats96<<<512, 192, 0, stream>>>(out, stats + 5 * 192);
    k_bnapply<96, 2, 0><<<eb96, 256, 0, stream>>>(out, stats + 5 * 192, g_out, b_out, x, nullptr);
}

// Round 6
// 1067.918 us; speedup vs baseline: 5.3130x; 1.1254x over previous
//
#include <hip/hip_runtime.h>
#include <math.h>

#define N_  100000
#define P_  96
#define V_  4
#define M_  70000
#define K_  43
#define KC_ 27

typedef unsigned short u16;
typedef __attribute__((ext_vector_type(8))) short bf16x8;
typedef __attribute__((ext_vector_type(4))) float f32x4;

__device__ __forceinline__ u16 f2bf(float f) {
    unsigned int u = __float_as_uint(f);
    u += 0x7fffu + ((u >> 16) & 1u);   // round-to-nearest-even
    return (u16)(u >> 16);
}
__device__ __forceinline__ float bf2f(u16 h) {
    return __uint_as_float(((unsigned int)h) << 16);
}

// ---------------------------------------------------------------------------
__global__ __launch_bounds__(256) void k_build_srcof(const int* __restrict__ km,
                                                     int* __restrict__ srcOf) {
    int idx = blockIdx.x * 256 + threadIdx.x;
    if (idx >= K_ * M_) return;
    int k = idx / M_;
    int e = idx - k * M_;
    const int* p = km + (size_t)(k * M_ + e) * 2;
    srcOf[(size_t)k * N_ + p[1]] = p[0];
}

// rowAbs[r] = sum_j |x[r][j]|  AND  xb = bf16(x)   (one wave per row)
__global__ __launch_bounds__(256) void k_rowabs_cvt(const float* __restrict__ x,
                                                    float* __restrict__ rowAbs,
                                                    u16* __restrict__ xb) {
    int row = blockIdx.x * 4 + (threadIdx.x >> 6);
    int lane = threadIdx.x & 63;
    if (row >= N_) return;
    const float* xr = x + (size_t)row * 96;
    float s = 0.f;
    for (int j = lane; j < 96; j += 64) {
        float v = xr[j];
        s += fabsf(v);
        xb[(size_t)row * 96 + j] = f2bf(v);
    }
#pragma unroll
    for (int o = 32; o > 0; o >>= 1) s += __shfl_down(s, o, 64);
    if (lane == 0) rowAbs[row] = s;
}

// Wt[k][n][j] = bf16(W[k][j][n])   (27 x 96 x 96)
__global__ __launch_bounds__(256) void k_wt96(const float* __restrict__ W,
                                              u16* __restrict__ Wt) {
    int idx = blockIdx.x * 256 + threadIdx.x;
    if (idx >= KC_ * 96 * 96) return;
    int k = idx / 9216, rem = idx - k * 9216, n = rem / 96, j = rem - n * 96;
    Wt[idx] = f2bf(W[(size_t)k * 9216 + j * 96 + n]);
}

// Wt4[k][n][j] = bf16(W[k][j][n]) for n<4 else 0   (27 x 16 x 96)
__global__ __launch_bounds__(256) void k_wt4(const float* __restrict__ W,
                                             u16* __restrict__ Wt) {
    int idx = blockIdx.x * 256 + threadIdx.x;
    if (idx >= KC_ * 16 * 96) return;
    int k = idx / 1536, rem = idx - k * 1536, n = rem / 96, j = rem - n * 96;
    Wt[idx] = (n < 4) ? f2bf(W[(size_t)k * 384 + j * 4 + n]) : (u16)0;
}

// w1b[j][c32] = bf16(W1[c][j]) c<4 else 0 (96x32); w2b[n16][j] = bf16(W2[j][n]) n<4 else 0
__global__ __launch_bounds__(256) void k_w12b(const float* __restrict__ W1,
                                              const float* __restrict__ W2,
                                              u16* __restrict__ w1b,
                                              u16* __restrict__ w2b) {
    int t = blockIdx.x * 256 + threadIdx.x;
    if (t < 96 * 32) {
        int j = t >> 5, c = t & 31;
        w1b[t] = (c < 4) ? f2bf(W1[c * 96 + j]) : (u16)0;
    }
    if (t < 16 * 96) {
        int n = t / 96, j = t - n * 96;
        w2b[t] = (n < 4) ? f2bf(W2[j * 4 + n]) : (u16)0;
    }
}

// ---------------------------------------------------------------------------
// Dual conv: yQ = conv(x, Wq1), yV = conv(x, Wv) sharing the gathered A rows.
// Outputs bf16; BN stats (sum/sumsq per channel) computed from f32 accs in
// the epilogue (shfl-reduce over quads -> LDS over waves -> 192 atomics/blk).
__global__ __launch_bounds__(256) void k_conv96_dual(
    const u16* __restrict__ xb, const u16* __restrict__ Wtq,
    const u16* __restrict__ Wtv, const int* __restrict__ srcOf,
    u16* __restrict__ yQ, u16* __restrict__ yV,
    float* __restrict__ statsQ, float* __restrict__ statsV) {
    __shared__ u16 sA[64 * 104];
    __shared__ u16 sBq[96 * 104];
    __shared__ u16 sBv[96 * 104];
    const int r0 = blockIdx.x * 64;
    const int t = threadIdx.x;
    const int wv = t >> 6, lane = t & 63;
    const int m = lane & 15, quad = lane >> 4;
    const int ea = t >> 2, jca = (t & 3) * 3;
    f32x4 accq[6], accv[6];
#pragma unroll
    for (int i = 0; i < 6; i++) {
        accq[i] = (f32x4){0.f, 0.f, 0.f, 0.f};
        accv[i] = (f32x4){0.f, 0.f, 0.f, 0.f};
    }

    for (int k = 0; k < KC_; k++) {
        __syncthreads();
        {   // stage A (shared by both convs)
            int r = r0 + ea;
            int src = (r < N_) ? srcOf[(size_t)k * N_ + r] : -1;
            if (src >= 0) {
                const uint4* sp = (const uint4*)(xb + (size_t)src * 96);
#pragma unroll
                for (int i = 0; i < 3; i++)
                    *(uint4*)(sA + ea * 104 + (jca + i) * 8) = sp[jca + i];
            } else {
                uint4 z = make_uint4(0, 0, 0, 0);
#pragma unroll
                for (int i = 0; i < 3; i++)
                    *(uint4*)(sA + ea * 104 + (jca + i) * 8) = z;
            }
        }
        {   // stage both B matrices
            const u16* wkq = Wtq + (size_t)k * 9216;
            const u16* wkv = Wtv + (size_t)k * 9216;
#pragma unroll
            for (int i = 0; i < 5; i++) {
                int c = t + 256 * i;
                if (c < 1152) {
                    int n = c / 12, jc = c - n * 12;
                    *(uint4*)(sBq + n * 104 + jc * 8) = *(const uint4*)(wkq + n * 96 + jc * 8);
                    *(uint4*)(sBv + n * 104 + jc * 8) = *(const uint4*)(wkv + n * 96 + jc * 8);
                }
            }
        }
        __syncthreads();
#pragma unroll
        for (int kk = 0; kk < 3; kk++) {
            bf16x8 af = *(const bf16x8*)(sA + (wv * 16 + m) * 104 + kk * 32 + quad * 8);
#pragma unroll
            for (int nt = 0; nt < 6; nt++) {
                bf16x8 bq = *(const bf16x8*)(sBq + (nt * 16 + m) * 104 + kk * 32 + quad * 8);
                accq[nt] = __builtin_amdgcn_mfma_f32_16x16x32_bf16(af, bq, accq[nt], 0, 0, 0);
                bf16x8 bv = *(const bf16x8*)(sBv + (nt * 16 + m) * 104 + kk * 32 + quad * 8);
                accv[nt] = __builtin_amdgcn_mfma_f32_16x16x32_bf16(af, bv, accv[nt], 0, 0, 0);
            }
        }
    }
    // outputs (bf16)
#pragma unroll
    for (int nt = 0; nt < 6; nt++) {
#pragma unroll
        for (int rg = 0; rg < 4; rg++) {
            int r = r0 + wv * 16 + quad * 4 + rg;
            if (r < N_) {
                yQ[(size_t)r * 96 + nt * 16 + m] = f2bf(accq[nt][rg]);
                yV[(size_t)r * 96 + nt * 16 + m] = f2bf(accv[nt][rg]);
            }
        }
    }
    // fused BN stats (rows >= N_ contribute exact zeros)
    __syncthreads();
    float* sred = (float*)sA;   // 4 waves x 192 floats = 3 KB, reuses sA
#pragma unroll
    for (int pass = 0; pass < 2; pass++) {
        f32x4* acc = pass ? accv : accq;
        float* st = pass ? statsV : statsQ;
        float sv[6], qv[6];
#pragma unroll
        for (int nt = 0; nt < 6; nt++) {
            f32x4 a = acc[nt];
            sv[nt] = a[0] + a[1] + a[2] + a[3];
            qv[nt] = a[0] * a[0] + a[1] * a[1] + a[2] * a[2] + a[3] * a[3];
            sv[nt] += __shfl_xor(sv[nt], 16, 64);
            sv[nt] += __shfl_xor(sv[nt], 32, 64);
            qv[nt] += __shfl_xor(qv[nt], 16, 64);
            qv[nt] += __shfl_xor(qv[nt], 32, 64);
        }
        if (quad == 0) {
#pragma unroll
            for (int nt = 0; nt < 6; nt++) {
                int ch = nt * 16 + m;
                sred[wv * 192 + ch] = sv[nt];
                sred[wv * 192 + 96 + ch] = qv[nt];
            }
        }
        __syncthreads();
        if (t < 192) {
            float tot = sred[t] + sred[192 + t] + sred[384 + t] + sred[576 + t];
            atomicAdd(&st[t], tot);
        }
        __syncthreads();
    }
}

// 96->4 conv via MFMA (N padded to 16). 128 rows/block.
__global__ __launch_bounds__(256) void k_conv4_mfma(
    const u16* __restrict__ xbA, const u16* __restrict__ Wt4,
    const int* __restrict__ srcOf, float* __restrict__ qf) {
    __shared__ u16 sA[128 * 104];
    __shared__ u16 sB[16 * 104];
    const int r0 = blockIdx.x * 128;
    const int t = threadIdx.x;
    const int wv = t >> 6, lane = t & 63;
    const int m = lane & 15, quad = lane >> 4;
    const int ea = t >> 1, jca = (t & 1) * 6;
    f32x4 acc[2];
    acc[0] = (f32x4){0.f, 0.f, 0.f, 0.f};
    acc[1] = (f32x4){0.f, 0.f, 0.f, 0.f};
    for (int k = 0; k < KC_; k++) {
        __syncthreads();
        {
            int r = r0 + ea;
            int src = (r < N_) ? srcOf[(size_t)k * N_ + r] : -1;
            if (src >= 0) {
                const uint4* sp = (const uint4*)(xbA + (size_t)src * 96);
#pragma unroll
                for (int i = 0; i < 6; i++)
                    *(uint4*)(sA + ea * 104 + (jca + i) * 8) = sp[jca + i];
            } else {
                uint4 z = make_uint4(0, 0, 0, 0);
#pragma unroll
                for (int i = 0; i < 6; i++)
                    *(uint4*)(sA + ea * 104 + (jca + i) * 8) = z;
            }
        }
        if (t < 192) {
            int n = t / 12, jc = t - (t / 12) * 12;
            *(uint4*)(sB + n * 104 + jc * 8) =
                *(const uint4*)(Wt4 + (size_t)k * 1536 + n * 96 + jc * 8);
        }
        __syncthreads();
#pragma unroll
        for (int kk = 0; kk < 3; kk++) {
            bf16x8 bfr = *(const bf16x8*)(sB + m * 104 + kk * 32 + quad * 8);
#pragma unroll
            for (int rt = 0; rt < 2; rt++) {
                bf16x8 af = *(const bf16x8*)(sA + ((wv * 2 + rt) * 16 + m) * 104 + kk * 32 + quad * 8);
                acc[rt] = __builtin_amdgcn_mfma_f32_16x16x32_bf16(af, bfr, acc[rt], 0, 0, 0);
            }
        }
    }
    if (m < 4) {
#pragma unroll
        for (int rt = 0; rt < 2; rt++)
#pragma unroll
            for (int rg = 0; rg < 4; rg++) {
                int r = r0 + (wv * 2 + rt) * 16 + quad * 4 + rg;
                if (r < N_) qf[(size_t)r * 4 + m] = acc[rt][rg];
            }
    }
}

// ---------------------------------------------------------------------------
__global__ __launch_bounds__(192) void k_bnstats96(const float* __restrict__ xin,
                                                   float* __restrict__ stats) {
    __shared__ float sS[192], sQ[192];
    int t = threadIdx.x;
    int ch = t % 96, half = t / 96;
    float s = 0.f, q = 0.f;
    for (int r = blockIdx.x * 2 + half; r < N_; r += gridDim.x * 2) {
        float v = xin[(size_t)r * 96 + ch];
        s += v; q += v * v;
    }
    sS[t] = s; sQ[t] = q;
    __syncthreads();
    if (t < 96) {
        atomicAdd(&stats[ch], sS[t] + sS[t + 96]);
        atomicAdd(&stats[96 + ch], sQ[t] + sQ[t + 96]);
    }
}

__global__ __launch_bounds__(256) void k_bnstats4(const float* __restrict__ xin,
                                                  float* __restrict__ stats) {
    __shared__ float sS[256], sQ[256];
    int t = threadIdx.x;
    int c = t & 3, sub = t >> 2;
    float s = 0.f, q = 0.f;
    for (int r = blockIdx.x * 64 + sub; r < N_; r += gridDim.x * 64) {
        float v = xin[(size_t)r * 4 + c];
        s += v; q += v * v;
    }
    sS[t] = s; sQ[t] = q;
    __syncthreads();
    for (int off = 128; off >= 4; off >>= 1) {
        if (t < off) { sS[t] += sS[t + off]; sQ[t] += sQ[t + off]; }
        __syncthreads();
    }
    if (t < 4) {
        atomicAdd(&stats[t], sS[t]);
        atomicAdd(&stats[96 + t], sQ[t]);
    }
}

// f32 in/out (MODE 0: relu(bn)  MODE 2: relu(bn)+aux)
template <int C, int MODE>
__global__ __launch_bounds__(256) void k_bnapply(float* __restrict__ y,
                                                 const float* __restrict__ stats,
                                                 const float* __restrict__ g,
                                                 const float* __restrict__ b,
                                                 const float* __restrict__ aux) {
    int idx = blockIdx.x * 256 + threadIdx.x;
    if (idx >= N_ * C) return;
    int ch = idx % C;
    float mean = stats[ch] * (1.f / N_);
    float var = stats[96 + ch] * (1.f / N_) - mean * mean;
    float scale = g[ch] * rsqrtf(fmaxf(var, 0.f) + 1e-5f);
    float v = (y[idx] - mean) * scale + b[ch];
    v = fmaxf(v, 0.f);
    if (MODE == 2) v += aux[idx];
    y[idx] = v;
}

// bf16 in -> bf16 out, C=96. MODE 0: relu(bn)  MODE 1: relu(bn)+pe_repeat
template <int MODE>
__global__ __launch_bounds__(256) void k_bnapply96_b2b(
    const u16* __restrict__ yin, const float* __restrict__ stats,
    const float* __restrict__ g, const float* __restrict__ b,
    const float* __restrict__ aux, u16* __restrict__ yout) {
    int idx = blockIdx.x * 256 + threadIdx.x;
    if (idx >= N_ * 96) return;
    int ch = idx % 96;
    float mean = stats[ch] * (1.f / N_);
    float var = stats[96 + ch] * (1.f / N_) - mean * mean;
    float scale = g[ch] * rsqrtf(fmaxf(var, 0.f) + 1e-5f);
    float v = (bf2f(yin[idx]) - mean) * scale + b[ch];
    v = fmaxf(v, 0.f);
    if (MODE == 1) { int r = idx / 96; v += aux[(size_t)r * 4 + (ch / 24)]; }
    yout[idx] = f2bf(v);
}

__global__ __launch_bounds__(256) void k_pe1(const float* __restrict__ coords,
                                             const float* __restrict__ Wp1,
                                             float* __restrict__ out) {
    int idx = blockIdx.x * 256 + threadIdx.x;
    if (idx >= N_ * 96) return;
    int r = idx / 96, ch = idx - r * 96;
    float c0 = coords[r * 3], c1 = coords[r * 3 + 1], c2 = coords[r * 3 + 2];
    out[idx] = c0 * Wp1[ch] + c1 * Wp1[96 + ch] + c2 * Wp1[192 + ch];
}

__global__ __launch_bounds__(256) void k_pe2(const float* __restrict__ hin,
                                             const float* __restrict__ Wp2,
                                             float* __restrict__ out) {
    int idx = blockIdx.x * 256 + threadIdx.x;
    if (idx >= N_ * 4) return;
    int r = idx / 4, c = idx & 3;
    const float* hr = hin + (size_t)r * 96;
    float acc = 0.f;
#pragma unroll 4
    for (int j = 0; j < 96; j++) acc += hr[j] * Wp2[j * 4 + c];
    out[idx] = acc;
}

// ---------------------------------------------------------------------------
// MFMA attention logits (32 rows/block). LDS dieted: slog/probs in bf16,
// mask in u16 -> 27.4 KB -> 5 blocks/CU.
__global__ __launch_bounds__(256) void k_attn_logits_mfma(
    const float* __restrict__ qf, const int* __restrict__ srcOf,
    const float* __restrict__ rowAbs,
    const u16* __restrict__ w1b, const float* __restrict__ b1,
    const u16* __restrict__ w2b, const float* __restrict__ b2,
    u16* __restrict__ wb) {
    __shared__ u16 hbuf[4][16 * 104];
    __shared__ u16 slogb[32][176];   // bf16 masked logits, later probs [rL][k*4+c]
    __shared__ u16 smk16[32][44];
    const int t = threadIdx.x;
    const int wv = t >> 6, lane = t & 63;
    const int col = lane & 15, quad = lane >> 4;
    const int r0 = blockIdx.x * 32;   // N_ % 32 == 0

    bf16x8 w1f[6];
    float b1v[6];
#pragma unroll
    for (int nt = 0; nt < 6; nt++) {
        w1f[nt] = *(const bf16x8*)(w1b + (nt * 16 + col) * 32 + quad * 8);
        b1v[nt] = b1[nt * 16 + col];
    }
    bf16x8 w2f[3];
#pragma unroll
    for (int kk = 0; kk < 3; kk++)
        w2f[kk] = *(const bf16x8*)(w2b + col * 96 + kk * 32 + quad * 8);
    float b2v = b2[col & 3];

    u16* hb = hbuf[wv];
    for (int tt = 0; tt < 22; tt++) {
        int tileBase = (wv * 22 + tt) * 16;
        bf16x8 af = (bf16x8){0, 0, 0, 0, 0, 0, 0, 0};
        if (quad == 0) {
            int P = tileBase + col;
            int rL = P / 44, k = P - rL * 44;
            int kc = (k < 43) ? k : 42;
            int r = r0 + rL;
            int s = srcOf[(size_t)kc * N_ + r];
            if (k == 43) s = -1;
            int sc = (s >= 0) ? s : 0;
            float mk = (s >= 0 && rowAbs[sc] > 0.f) ? 1.f : 0.f;
            float4 qs = *(const float4*)(qf + (size_t)sc * 4);
            float4 qr = *(const float4*)(qf + (size_t)r * 4);
            af[0] = (short)f2bf((qs.x - qr.x) * mk);
            af[1] = (short)f2bf((qs.y - qr.y) * mk);
            af[2] = (short)f2bf((qs.z - qr.z) * mk);
            af[3] = (short)f2bf((qs.w - qr.w) * mk);
            if (k < 43) smk16[rL][k] = (u16)(mk > 0.f ? 1 : 0);
        }
        // GEMM1: h (16 pairs x 96)
        f32x4 c1[6];
#pragma unroll
        for (int nt = 0; nt < 6; nt++) {
            c1[nt] = (f32x4){0.f, 0.f, 0.f, 0.f};
            c1[nt] = __builtin_amdgcn_mfma_f32_16x16x32_bf16(af, w1f[nt], c1[nt], 0, 0, 0);
        }
#pragma unroll
        for (int nt = 0; nt < 6; nt++) {
#pragma unroll
            for (int rg = 0; rg < 4; rg++) {
                float h = fmaxf(c1[nt][rg] + b1v[nt], 0.f);
                hb[(quad * 4 + rg) * 104 + nt * 16 + col] = f2bf(h);
            }
        }
        // GEMM2: logits (16 pairs x 4-of-16), K=96
        f32x4 acc2 = (f32x4){0.f, 0.f, 0.f, 0.f};
#pragma unroll
        for (int kk = 0; kk < 3; kk++) {
            bf16x8 a2 = *(const bf16x8*)(hb + col * 104 + kk * 32 + quad * 8);
            acc2 = __builtin_amdgcn_mfma_f32_16x16x32_bf16(a2, w2f[kk], acc2, 0, 0, 0);
        }
        if (col < 4) {
#pragma unroll
            for (int rg = 0; rg < 4; rg++) {
                int P = tileBase + quad * 4 + rg;
                int rL = P / 44, k = P - rL * 44;
                if (k < 43) {
                    float mval = (float)smk16[rL][k];
                    slogb[rL][k * 4 + col] = f2bf((acc2[rg] + b2v) * mval);
                }
            }
        }
    }
    __syncthreads();

    // softmax over k (uncovered entries contribute exp(0)), bf16 in -> probs bf16
    if (t < 128) {
        int rL = t >> 2, c = t & 3;
        float mx = 0.f;
        for (int k = 0; k < K_; k++) mx = fmaxf(mx, bf2f(slogb[rL][k * 4 + c]));
        float den = 0.f;
        for (int k = 0; k < K_; k++) den += __expf(bf2f(slogb[rL][k * 4 + c]) - mx);
        float inv = 1.f / den;
        for (int k = 0; k < K_; k++)
            slogb[rL][k * 4 + c] = f2bf(__expf(bf2f(slogb[rL][k * 4 + c]) - mx) * inv);
    }
    __syncthreads();

    // wb[r][k][c] = mask * probs[ATTN_IDX[k]][c]
    for (int p = t; p < 32 * 43; p += 256) {
        int rL = p / 43, k = p - rL * 43;
        int idxk = (k < 27) ? k : ((k < 35) ? (k - 27) : (k - 35));
        u16 mk = smk16[rL][k];
        ushort4 wout = make_ushort4(0, 0, 0, 0);
        if (mk) {
            wout.x = slogb[rL][idxk * 4 + 0];
            wout.y = slogb[rL][idxk * 4 + 1];
            wout.z = slogb[rL][idxk * 4 + 2];
            wout.w = slogb[rL][idxk * 4 + 3];
        }
        *(ushort4*)(wb + ((size_t)(r0 + rL) * 44 + k) * 4) = wout;
    }
}

// out[r][ch] = sum_k wb[r][k][cg] * vfb[src_k[r]][ch]
__global__ __launch_bounds__(256) void k_attn_gather(
    const u16* __restrict__ vfb, const u16* __restrict__ wb,
    const int* __restrict__ srcOf, float* __restrict__ out) {
    int idx = blockIdx.x * 256 + threadIdx.x;
    int r = idx / 24, c4 = idx - r * 24;
    if (r >= N_) return;
    int cg = c4 / 6;
    const u16* wrow = wb + (size_t)r * 176 + cg;
    float a0 = 0.f, a1 = 0.f, a2 = 0.f, a3 = 0.f;
    for (int k = 0; k < K_; k++) {
        int s = srcOf[(size_t)k * N_ + r];
        float w = bf2f(wrow[(size_t)k * 4]);
        w = (s >= 0) ? w : 0.f;
        int sc = (s >= 0) ? s : 0;
        ushort4 v = *(const ushort4*)(vfb + (size_t)sc * 96 + c4 * 4);
        a0 += w * bf2f(v.x);
        a1 += w * bf2f(v.y);
        a2 += w * bf2f(v.z);
        a3 += w * bf2f(v.w);
    }
    *(float4*)(out + (size_t)r * 96 + c4 * 4) = make_float4(a0, a1, a2, a3);
}

// ---------------------------------------------------------------------------
extern "C" void kernel_launch(void* const* d_in, const int* in_sizes, int n_in,
                              void* d_out, int out_size, void* d_ws, size_t ws_size,
                              hipStream_t stream) {
    const float* x      = (const float*)d_in[0];
    const float* coords = (const float*)d_in[1];
    const float* Wq1 = (const float*)d_in[2];
    const float* gq1 = (const float*)d_in[3];
    const float* bq1 = (const float*)d_in[4];
    const float* Wq2 = (const float*)d_in[5];
    const float* gq2 = (const float*)d_in[6];
    const float* bq2 = (const float*)d_in[7];
    const float* Wv  = (const float*)d_in[8];
    const float* gv  = (const float*)d_in[9];
    const float* bv  = (const float*)d_in[10];
    const float* Wp1 = (const float*)d_in[11];
    const float* gp1 = (const float*)d_in[12];
    const float* bp1 = (const float*)d_in[13];
    const float* Wp2 = (const float*)d_in[14];
    const float* gp2 = (const float*)d_in[15];
    const float* bp2 = (const float*)d_in[16];
    const float* W1  = (const float*)d_in[17];
    const float* b1  = (const float*)d_in[18];
    const float* W2  = (const float*)d_in[19];
    const float* b2  = (const float*)d_in[20];
    const float* g_out = (const float*)d_in[21];
    const float* b_out = (const float*)d_in[22];
    const int* kmaps = (const int*)d_in[23];
    float* out = (float*)d_out;

    char* ws = (char*)d_ws;
    int*   srcOf  = (int*)ws;                        //  0        + 17,200,000
    float* rowAbs = (float*)(ws + 17200000);         //           +    400,000
    u16*   xb     = (u16*)(ws + 17600000);           //           + 19,200,000
    u16*   bufQb  = (u16*)(ws + 36800000);           //           + 19,200,000
    u16*   bufVb  = (u16*)(ws + 56000000);           //           + 19,200,000
    u16*   bufAb  = (u16*)(ws + 75200000);           //           + 19,200,000
    u16*   vfb    = (u16*)(ws + 75200000);           // overlays bufAb (dead after conv4)
    float* pescr  = (float*)(ws + 17600000);         // overlays xb+bufQb (dead after bnapply-Q)
    u16*   wbuf   = (u16*)(ws + 17600000);           // overlays pescr (dead after pe2)
    float* qf     = (float*)(ws + 94400000);         //           +  1,600,000
    float* peb    = (float*)(ws + 96000000);         //           +  1,600,000
    u16*   Wq1t   = (u16*)(ws + 97600000);           //           +    497,664
    u16*   Wvt    = (u16*)(ws + 98097664);           //           +    497,664
    u16*   Wq2t   = (u16*)(ws + 98595328);           //           +     82,944
    u16*   w1b    = (u16*)(ws + 98678272);           //           +      6,144
    u16*   w2b    = (u16*)(ws + 98684416);           //           +      3,072
    float* stats  = (float*)(ws + 98687488);         //           +      4,608

    hipMemsetAsync(srcOf, 0xFF, (size_t)K_ * N_ * 4, stream);  // -1
    hipMemsetAsync(stats, 0, 6 * 192 * 4, stream);

    k_build_srcof<<<(K_ * M_ + 255) / 256, 256, 0, stream>>>(kmaps, srcOf);
    k_rowabs_cvt<<<N_ / 4, 256, 0, stream>>>(x, rowAbs, xb);
    k_wt96<<<(KC_ * 9216 + 255) / 256, 256, 0, stream>>>(Wq1, Wq1t);
    k_wt96<<<(KC_ * 9216 + 255) / 256, 256, 0, stream>>>(Wv, Wvt);
    k_wt4<<<(KC_ * 1536 + 255) / 256, 256, 0, stream>>>(Wq2, Wq2t);
    k_w12b<<<12, 256, 0, stream>>>(W1, W2, w1b, w2b);

    const int cb96 = (N_ + 63) / 64;     // 1563
    const int cb4  = (N_ + 127) / 128;   // 782
    const int eb96 = N_ * 96 / 256;      // 37500
    const int eb4  = (N_ * 4 + 255) / 256;

    // both convs + their BN stats in one pass
    k_conv96_dual<<<cb96, 256, 0, stream>>>(xb, Wq1t, Wvt, srcOf, bufQb, bufVb,
                                            stats + 0 * 192, stats + 4 * 192);

    // q-branch: bn+relu -> conv4 -> bn
    k_bnapply96_b2b<0><<<eb96, 256, 0, stream>>>(bufQb, stats + 0 * 192, gq1, bq1, nullptr, bufAb);
    k_conv4_mfma<<<cb4, 256, 0, stream>>>(bufAb, Wq2t, srcOf, qf);
    k_bnstats4<<<512, 256, 0, stream>>>(qf, stats + 1 * 192);
    k_bnapply<4, 0><<<eb4, 256, 0, stream>>>(qf, stats + 1 * 192, gq2, bq2, nullptr);

    // pe chain (pescr overlays xb+bufQb, both dead by now)
    k_pe1<<<eb96, 256, 0, stream>>>(coords, Wp1, pescr);
    k_bnstats96<<<512, 192, 0, stream>>>(pescr, stats + 2 * 192);
    k_bnapply<96, 0><<<eb96, 256, 0, stream>>>(pescr, stats + 2 * 192, gp1, bp1, nullptr);
    k_pe2<<<eb4, 256, 0, stream>>>(pescr, Wp2, peb);
    k_bnstats4<<<512, 256, 0, stream>>>(peb, stats + 3 * 192);
    k_bnapply<4, 0><<<eb4, 256, 0, stream>>>(peb, stats + 3 * 192, gp2, bp2, nullptr);

    // v-branch: bn+relu+pe -> vfb (bf16 only; overlays bufAb after conv4)
    k_bnapply96_b2b<1><<<eb96, 256, 0, stream>>>(bufVb, stats + 4 * 192, gv, bv, peb, vfb);

    // attention
    k_attn_logits_mfma<<<N_ / 32, 256, 0, stream>>>(qf, srcOf, rowAbs, w1b, b1, w2b, b2, wbuf);
    k_attn_gather<<<(N_ * 24) / 256, 256, 0, stream>>>(vfb, wbuf, srcOf, out);

    // out = relu(bn(out)) + x
    k_bnstats96<<<512, 192, 0, stream>>>(out, stats + 5 * 192);
    k_bnapply<96, 2><<<eb96, 256, 0, stream>>>(out, stats + 5 * 192, g_out, b_out, x);
}

// Round 7
// 995.989 us; speedup vs baseline: 5.6967x; 1.0722x over previous
//
#include <hip/hip_runtime.h>
#include <math.h>

#define N_  100000
#define P_  96
#define V_  4
#define M_  70000
#define K_  43
#define KC_ 27

typedef unsigned short u16;
typedef __attribute__((ext_vector_type(8))) short bf16x8;
typedef __attribute__((ext_vector_type(4))) float f32x4;
typedef __attribute__((ext_vector_type(16))) float f32x16;

__device__ __forceinline__ u16 f2bf(float f) {
    unsigned int u = __float_as_uint(f);
    u += 0x7fffu + ((u >> 16) & 1u);   // round-to-nearest-even
    return (u16)(u >> 16);
}
__device__ __forceinline__ float bf2f(u16 h) {
    return __uint_as_float(((unsigned int)h) << 16);
}

// async global->LDS DMA, 16 B per lane; dest = wave-uniform base + lane*16
__device__ __forceinline__ void gl_lds16(const u16* g, u16* l) {
    __builtin_amdgcn_global_load_lds(
        (const __attribute__((address_space(1))) void*)g,
        (__attribute__((address_space(3))) void*)l, 16, 0, 0);
}

// ---------------------------------------------------------------------------
__global__ __launch_bounds__(256) void k_build_srcof(const int* __restrict__ km,
                                                     int* __restrict__ srcOf) {
    int idx = blockIdx.x * 256 + threadIdx.x;
    if (idx >= K_ * M_) return;
    int k = idx / M_;
    int e = idx - k * M_;
    const int* p = km + (size_t)(k * M_ + e) * 2;
    srcOf[(size_t)k * N_ + p[1]] = p[0];
}

// rowAbs[r] = sum_j |x[r][j]|  AND  xb = bf16(x)
__global__ __launch_bounds__(256) void k_rowabs_cvt(const float* __restrict__ x,
                                                    float* __restrict__ rowAbs,
                                                    u16* __restrict__ xb) {
    int row = blockIdx.x * 4 + (threadIdx.x >> 6);
    int lane = threadIdx.x & 63;
    if (row >= N_) return;
    const float* xr = x + (size_t)row * 96;
    float s = 0.f;
    for (int j = lane; j < 96; j += 64) {
        float v = xr[j];
        s += fabsf(v);
        xb[(size_t)row * 96 + j] = f2bf(v);
    }
#pragma unroll
    for (int o = 32; o > 0; o >>= 1) s += __shfl_down(s, o, 64);
    if (lane == 0) rowAbs[row] = s;
}

// Padded weight image for async staging: Wp[k*10240 + n*104 + j] = bf16(W[k][j][n])
// (stride 104 baked into GLOBAL layout so global_load_lds's linear copy lands
//  the padded LDS layout; per-k image rounded to 20480 B = 20 wave-issues)
__global__ __launch_bounds__(256) void k_wt96p(const float* __restrict__ W,
                                               u16* __restrict__ Wp) {
    int idx = blockIdx.x * 256 + threadIdx.x;
    if (idx >= KC_ * 96 * 96) return;
    int k = idx / 9216, rem = idx - k * 9216, n = rem / 96, j = rem - n * 96;
    Wp[(size_t)k * 10240 + n * 104 + j] = f2bf(W[(size_t)k * 9216 + j * 96 + n]);
}

// Wt4[k][n][j] = bf16(W[k][j][n]) for n<4 else 0   (27 x 16 x 96)
__global__ __launch_bounds__(256) void k_wt4(const float* __restrict__ W,
                                             u16* __restrict__ Wt) {
    int idx = blockIdx.x * 256 + threadIdx.x;
    if (idx >= KC_ * 16 * 96) return;
    int k = idx / 1536, rem = idx - k * 1536, n = rem / 96, j = rem - n * 96;
    Wt[idx] = (n < 4) ? f2bf(W[(size_t)k * 384 + j * 4 + n]) : (u16)0;
}

// w1b[j][c32] = bf16(W1[c][j]) c<4 else 0; w2b[n16][j] = bf16(W2[j][n]) n<4 else 0
__global__ __launch_bounds__(256) void k_w12b(const float* __restrict__ W1,
                                              const float* __restrict__ W2,
                                              u16* __restrict__ w1b,
                                              u16* __restrict__ w2b) {
    int t = blockIdx.x * 256 + threadIdx.x;
    if (t < 96 * 32) {
        int j = t >> 5, c = t & 31;
        w1b[t] = (c < 4) ? f2bf(W1[c * 96 + j]) : (u16)0;
    }
    if (t < 16 * 96) {
        int n = t / 96, j = t - n * 96;
        w2b[t] = (n < 4) ? f2bf(W2[j * 4 + n]) : (u16)0;
    }
}

// ---------------------------------------------------------------------------
// Dual conv, 32x32x16 MFMA, 192 rows/block, 384 threads (6 waves x 1 M-tile).
// B staged async via global_load_lds from padded images; A gathered via ds_write.
// BN stats fused in epilogue.
__global__ __launch_bounds__(384, 3) void k_conv96_dual(
    const u16* __restrict__ xb, const u16* __restrict__ Wqp,
    const u16* __restrict__ Wvp, const int* __restrict__ srcOf,
    u16* __restrict__ yQ, u16* __restrict__ yV,
    float* __restrict__ statsQ, float* __restrict__ statsV) {
    __shared__ u16 sA[192 * 104];   // 39,936 B
    __shared__ u16 sBq[10240];      // 20,480 B (96x104 padded image)
    __shared__ u16 sBv[10240];      // 20,480 B
    const int r0 = blockIdx.x * 192;
    const int t = threadIdx.x;
    const int wv = t / 64, lane = t & 63;
    const int n32 = lane & 31, half = lane >> 5;
    const int ea = t >> 1, jca = (t & 1) * 6;
    f32x16 accq[3], accv[3];
#pragma unroll
    for (int i = 0; i < 3; i++) {
#pragma unroll
        for (int j = 0; j < 16; j++) { accq[i][j] = 0.f; accv[i][j] = 0.f; }
    }

    for (int k = 0; k < KC_; k++) {
        __syncthreads();
        // --- B: async DMA, 40 wave-issues of 1 KB split across 6 waves
        {
            const u16* gq = Wqp + (size_t)k * 10240;
            const u16* gv = Wvp + (size_t)k * 10240;
            for (int i = wv; i < 40; i += 6) {
                int mv = (i >= 20);
                int off = (mv ? i - 20 : i) * 512 + lane * 8;
                gl_lds16((mv ? gv : gq) + off, (mv ? (u16*)sBv : (u16*)sBq) + off);
            }
        }
        // --- A: gathered rows (2 threads per row, 6 x 16B each)
        {
            int r = r0 + ea;
            int src = (r < N_) ? srcOf[(size_t)k * N_ + r] : -1;
            if (src >= 0) {
                const uint4* sp = (const uint4*)(xb + (size_t)src * 96);
#pragma unroll
                for (int i = 0; i < 6; i++)
                    *(uint4*)(sA + ea * 104 + (jca + i) * 8) = sp[jca + i];
            } else {
                uint4 z = make_uint4(0, 0, 0, 0);
#pragma unroll
                for (int i = 0; i < 6; i++)
                    *(uint4*)(sA + ea * 104 + (jca + i) * 8) = z;
            }
        }
        __syncthreads();   // drains vmcnt (DMA) + lgkmcnt (ds_write)
        // --- MFMA: 6 K-steps x 3 n-tiles x 2 matrices
#pragma unroll
        for (int ks = 0; ks < 6; ks++) {
            bf16x8 af = *(const bf16x8*)(sA + (wv * 32 + n32) * 104 + ks * 16 + half * 8);
#pragma unroll
            for (int nt = 0; nt < 3; nt++) {
                bf16x8 bq = *(const bf16x8*)(sBq + (nt * 32 + n32) * 104 + ks * 16 + half * 8);
                accq[nt] = __builtin_amdgcn_mfma_f32_32x32x16_bf16(af, bq, accq[nt], 0, 0, 0);
                bf16x8 bv = *(const bf16x8*)(sBv + (nt * 32 + n32) * 104 + ks * 16 + half * 8);
                accv[nt] = __builtin_amdgcn_mfma_f32_32x32x16_bf16(af, bv, accv[nt], 0, 0, 0);
            }
        }
    }
    // --- outputs (bf16); C/D: col=lane&31, row=(reg&3)+8*(reg>>2)+4*half
#pragma unroll
    for (int nt = 0; nt < 3; nt++) {
#pragma unroll
        for (int reg = 0; reg < 16; reg++) {
            int row = (reg & 3) + 8 * (reg >> 2) + 4 * half;
            int r = r0 + wv * 32 + row;
            if (r < N_) {
                yQ[(size_t)r * 96 + nt * 32 + n32] = f2bf(accq[nt][reg]);
                yV[(size_t)r * 96 + nt * 32 + n32] = f2bf(accv[nt][reg]);
            }
        }
    }
    // --- fused BN stats (invalid rows contribute exact zeros)
    __syncthreads();
    float* sred = (float*)sA;   // 6 waves x 192 floats
    for (int pass = 0; pass < 2; pass++) {
        f32x16* acc = pass ? accv : accq;
        float* st = pass ? statsV : statsQ;
#pragma unroll
        for (int nt = 0; nt < 3; nt++) {
            float sv = 0.f, qv = 0.f;
#pragma unroll
            for (int reg = 0; reg < 16; reg++) {
                float a = acc[nt][reg];
                sv += a; qv += a * a;
            }
            sv += __shfl_xor(sv, 32, 64);
            qv += __shfl_xor(qv, 32, 64);
            if (half == 0) {
                sred[wv * 192 + nt * 32 + n32] = sv;
                sred[wv * 192 + 96 + nt * 32 + n32] = qv;
            }
        }
        __syncthreads();
        if (t < 192) {
            float tot = 0.f;
#pragma unroll
            for (int w = 0; w < 6; w++) tot += sred[w * 192 + t];
            atomicAdd(&st[t], tot);
        }
        __syncthreads();
    }
}

// 96->4 conv via MFMA (N padded to 16). 128 rows/block.
__global__ __launch_bounds__(256) void k_conv4_mfma(
    const u16* __restrict__ xbA, const u16* __restrict__ Wt4,
    const int* __restrict__ srcOf, float* __restrict__ qf) {
    __shared__ u16 sA[128 * 104];
    __shared__ u16 sB[16 * 104];
    const int r0 = blockIdx.x * 128;
    const int t = threadIdx.x;
    const int wv = t >> 6, lane = t & 63;
    const int m = lane & 15, quad = lane >> 4;
    const int ea = t >> 1, jca = (t & 1) * 6;
    f32x4 acc[2];
    acc[0] = (f32x4){0.f, 0.f, 0.f, 0.f};
    acc[1] = (f32x4){0.f, 0.f, 0.f, 0.f};
    for (int k = 0; k < KC_; k++) {
        __syncthreads();
        {
            int r = r0 + ea;
            int src = (r < N_) ? srcOf[(size_t)k * N_ + r] : -1;
            if (src >= 0) {
                const uint4* sp = (const uint4*)(xbA + (size_t)src * 96);
#pragma unroll
                for (int i = 0; i < 6; i++)
                    *(uint4*)(sA + ea * 104 + (jca + i) * 8) = sp[jca + i];
            } else {
                uint4 z = make_uint4(0, 0, 0, 0);
#pragma unroll
                for (int i = 0; i < 6; i++)
                    *(uint4*)(sA + ea * 104 + (jca + i) * 8) = z;
            }
        }
        if (t < 192) {
            int n = t / 12, jc = t - (t / 12) * 12;
            *(uint4*)(sB + n * 104 + jc * 8) =
                *(const uint4*)(Wt4 + (size_t)k * 1536 + n * 96 + jc * 8);
        }
        __syncthreads();
#pragma unroll
        for (int kk = 0; kk < 3; kk++) {
            bf16x8 bfr = *(const bf16x8*)(sB + m * 104 + kk * 32 + quad * 8);
#pragma unroll
            for (int rt = 0; rt < 2; rt++) {
                bf16x8 af = *(const bf16x8*)(sA + ((wv * 2 + rt) * 16 + m) * 104 + kk * 32 + quad * 8);
                acc[rt] = __builtin_amdgcn_mfma_f32_16x16x32_bf16(af, bfr, acc[rt], 0, 0, 0);
            }
        }
    }
    if (m < 4) {
#pragma unroll
        for (int rt = 0; rt < 2; rt++)
#pragma unroll
            for (int rg = 0; rg < 4; rg++) {
                int r = r0 + (wv * 2 + rt) * 16 + quad * 4 + rg;
                if (r < N_) qf[(size_t)r * 4 + m] = acc[rt][rg];
            }
    }
}

// ---------------------------------------------------------------------------
__global__ __launch_bounds__(192) void k_bnstats96(const float* __restrict__ xin,
                                                   float* __restrict__ stats) {
    __shared__ float sS[192], sQ[192];
    int t = threadIdx.x;
    int ch = t % 96, half = t / 96;
    float s = 0.f, q = 0.f;
    for (int r = blockIdx.x * 2 + half; r < N_; r += gridDim.x * 2) {
        float v = xin[(size_t)r * 96 + ch];
        s += v; q += v * v;
    }
    sS[t] = s; sQ[t] = q;
    __syncthreads();
    if (t < 96) {
        atomicAdd(&stats[ch], sS[t] + sS[t + 96]);
        atomicAdd(&stats[96 + ch], sQ[t] + sQ[t + 96]);
    }
}

__global__ __launch_bounds__(256) void k_bnstats4(const float* __restrict__ xin,
                                                  float* __restrict__ stats) {
    __shared__ float sS[256], sQ[256];
    int t = threadIdx.x;
    int c = t & 3, sub = t >> 2;
    float s = 0.f, q = 0.f;
    for (int r = blockIdx.x * 64 + sub; r < N_; r += gridDim.x * 64) {
        float v = xin[(size_t)r * 4 + c];
        s += v; q += v * v;
    }
    sS[t] = s; sQ[t] = q;
    __syncthreads();
    for (int off = 128; off >= 4; off >>= 1) {
        if (t < off) { sS[t] += sS[t + off]; sQ[t] += sQ[t + off]; }
        __syncthreads();
    }
    if (t < 4) {
        atomicAdd(&stats[t], sS[t]);
        atomicAdd(&stats[96 + t], sQ[t]);
    }
}

// f32 in/out (MODE 0: relu(bn)  MODE 2: relu(bn)+aux)
template <int C, int MODE>
__global__ __launch_bounds__(256) void k_bnapply(float* __restrict__ y,
                                                 const float* __restrict__ stats,
                                                 const float* __restrict__ g,
                                                 const float* __restrict__ b,
                                                 const float* __restrict__ aux) {
    int idx = blockIdx.x * 256 + threadIdx.x;
    if (idx >= N_ * C) return;
    int ch = idx % C;
    float mean = stats[ch] * (1.f / N_);
    float var = stats[96 + ch] * (1.f / N_) - mean * mean;
    float scale = g[ch] * rsqrtf(fmaxf(var, 0.f) + 1e-5f);
    float v = (y[idx] - mean) * scale + b[ch];
    v = fmaxf(v, 0.f);
    if (MODE == 2) v += aux[idx];
    y[idx] = v;
}

// bf16 in -> bf16 out, C=96. MODE 0: relu(bn)  MODE 1: relu(bn)+pe_repeat
template <int MODE>
__global__ __launch_bounds__(256) void k_bnapply96_b2b(
    const u16* __restrict__ yin, const float* __restrict__ stats,
    const float* __restrict__ g, const float* __restrict__ b,
    const float* __restrict__ aux, u16* __restrict__ yout) {
    int idx = blockIdx.x * 256 + threadIdx.x;
    if (idx >= N_ * 96) return;
    int ch = idx % 96;
    float mean = stats[ch] * (1.f / N_);
    float var = stats[96 + ch] * (1.f / N_) - mean * mean;
    float scale = g[ch] * rsqrtf(fmaxf(var, 0.f) + 1e-5f);
    float v = (bf2f(yin[idx]) - mean) * scale + b[ch];
    v = fmaxf(v, 0.f);
    if (MODE == 1) { int r = idx / 96; v += aux[(size_t)r * 4 + (ch / 24)]; }
    yout[idx] = f2bf(v);
}

__global__ __launch_bounds__(256) void k_pe1(const float* __restrict__ coords,
                                             const float* __restrict__ Wp1,
                                             float* __restrict__ out) {
    int idx = blockIdx.x * 256 + threadIdx.x;
    if (idx >= N_ * 96) return;
    int r = idx / 96, ch = idx - r * 96;
    float c0 = coords[r * 3], c1 = coords[r * 3 + 1], c2 = coords[r * 3 + 2];
    out[idx] = c0 * Wp1[ch] + c1 * Wp1[96 + ch] + c2 * Wp1[192 + ch];
}

__global__ __launch_bounds__(256) void k_pe2(const float* __restrict__ hin,
                                             const float* __restrict__ Wp2,
                                             float* __restrict__ out) {
    int idx = blockIdx.x * 256 + threadIdx.x;
    if (idx >= N_ * 4) return;
    int r = idx / 4, c = idx & 3;
    const float* hr = hin + (size_t)r * 96;
    float acc = 0.f;
#pragma unroll 4
    for (int j = 0; j < 96; j++) acc += hr[j] * Wp2[j * 4 + c];
    out[idx] = acc;
}

// ---------------------------------------------------------------------------
// MFMA attention logits (32 rows/block), bf16 LDS softmax state.
__global__ __launch_bounds__(256) void k_attn_logits_mfma(
    const float* __restrict__ qf, const int* __restrict__ srcOf,
    const float* __restrict__ rowAbs,
    const u16* __restrict__ w1b, const float* __restrict__ b1,
    const u16* __restrict__ w2b, const float* __restrict__ b2,
    u16* __restrict__ wb) {
    __shared__ u16 hbuf[4][16 * 104];
    __shared__ u16 slogb[32][176];
    __shared__ u16 smk16[32][44];
    const int t = threadIdx.x;
    const int wv = t >> 6, lane = t & 63;
    const int col = lane & 15, quad = lane >> 4;
    const int r0 = blockIdx.x * 32;

    bf16x8 w1f[6];
    float b1v[6];
#pragma unroll
    for (int nt = 0; nt < 6; nt++) {
        w1f[nt] = *(const bf16x8*)(w1b + (nt * 16 + col) * 32 + quad * 8);
        b1v[nt] = b1[nt * 16 + col];
    }
    bf16x8 w2f[3];
#pragma unroll
    for (int kk = 0; kk < 3; kk++)
        w2f[kk] = *(const bf16x8*)(w2b + col * 96 + kk * 32 + quad * 8);
    float b2v = b2[col & 3];

    u16* hb = hbuf[wv];
    for (int tt = 0; tt < 22; tt++) {
        int tileBase = (wv * 22 + tt) * 16;
        bf16x8 af = (bf16x8){0, 0, 0, 0, 0, 0, 0, 0};
        if (quad == 0) {
            int P = tileBase + col;
            int rL = P / 44, k = P - rL * 44;
            int kc = (k < 43) ? k : 42;
            int r = r0 + rL;
            int s = srcOf[(size_t)kc * N_ + r];
            if (k == 43) s = -1;
            int sc = (s >= 0) ? s : 0;
            float mk = (s >= 0 && rowAbs[sc] > 0.f) ? 1.f : 0.f;
            float4 qs = *(const float4*)(qf + (size_t)sc * 4);
            float4 qr = *(const float4*)(qf + (size_t)r * 4);
            af[0] = (short)f2bf((qs.x - qr.x) * mk);
            af[1] = (short)f2bf((qs.y - qr.y) * mk);
            af[2] = (short)f2bf((qs.z - qr.z) * mk);
            af[3] = (short)f2bf((qs.w - qr.w) * mk);
            if (k < 43) smk16[rL][k] = (u16)(mk > 0.f ? 1 : 0);
        }
        f32x4 c1[6];
#pragma unroll
        for (int nt = 0; nt < 6; nt++) {
            c1[nt] = (f32x4){0.f, 0.f, 0.f, 0.f};
            c1[nt] = __builtin_amdgcn_mfma_f32_16x16x32_bf16(af, w1f[nt], c1[nt], 0, 0, 0);
        }
#pragma unroll
        for (int nt = 0; nt < 6; nt++) {
#pragma unroll
            for (int rg = 0; rg < 4; rg++) {
                float h = fmaxf(c1[nt][rg] + b1v[nt], 0.f);
                hb[(quad * 4 + rg) * 104 + nt * 16 + col] = f2bf(h);
            }
        }
        f32x4 acc2 = (f32x4){0.f, 0.f, 0.f, 0.f};
#pragma unroll
        for (int kk = 0; kk < 3; kk++) {
            bf16x8 a2 = *(const bf16x8*)(hb + col * 104 + kk * 32 + quad * 8);
            acc2 = __builtin_amdgcn_mfma_f32_16x16x32_bf16(a2, w2f[kk], acc2, 0, 0, 0);
        }
        if (col < 4) {
#pragma unroll
            for (int rg = 0; rg < 4; rg++) {
                int P = tileBase + quad * 4 + rg;
                int rL = P / 44, k = P - rL * 44;
                if (k < 43) {
                    float mval = (float)smk16[rL][k];
                    slogb[rL][k * 4 + col] = f2bf((acc2[rg] + b2v) * mval);
                }
            }
        }
    }
    __syncthreads();

    if (t < 128) {
        int rL = t >> 2, c = t & 3;
        float mx = 0.f;
        for (int k = 0; k < K_; k++) mx = fmaxf(mx, bf2f(slogb[rL][k * 4 + c]));
        float den = 0.f;
        for (int k = 0; k < K_; k++) den += __expf(bf2f(slogb[rL][k * 4 + c]) - mx);
        float inv = 1.f / den;
        for (int k = 0; k < K_; k++)
            slogb[rL][k * 4 + c] = f2bf(__expf(bf2f(slogb[rL][k * 4 + c]) - mx) * inv);
    }
    __syncthreads();

    for (int p = t; p < 32 * 43; p += 256) {
        int rL = p / 43, k = p - rL * 43;
        int idxk = (k < 27) ? k : ((k < 35) ? (k - 27) : (k - 35));
        u16 mk = smk16[rL][k];
        ushort4 wout = make_ushort4(0, 0, 0, 0);
        if (mk) {
            wout.x = slogb[rL][idxk * 4 + 0];
            wout.y = slogb[rL][idxk * 4 + 1];
            wout.z = slogb[rL][idxk * 4 + 2];
            wout.w = slogb[rL][idxk * 4 + 3];
        }
        *(ushort4*)(wb + ((size_t)(r0 + rL) * 44 + k) * 4) = wout;
    }
}

// out[r][ch] = sum_k wb[r][k][cg] * vfb[src_k[r]][ch]
__global__ __launch_bounds__(256) void k_attn_gather(
    const u16* __restrict__ vfb, const u16* __restrict__ wb,
    const int* __restrict__ srcOf, float* __restrict__ out) {
    int idx = blockIdx.x * 256 + threadIdx.x;
    int r = idx / 24, c4 = idx - r * 24;
    if (r >= N_) return;
    int cg = c4 / 6;
    const u16* wrow = wb + (size_t)r * 176 + cg;
    float a0 = 0.f, a1 = 0.f, a2 = 0.f, a3 = 0.f;
    for (int k = 0; k < K_; k++) {
        int s = srcOf[(size_t)k * N_ + r];
        float w = bf2f(wrow[(size_t)k * 4]);
        w = (s >= 0) ? w : 0.f;
        int sc = (s >= 0) ? s : 0;
        ushort4 v = *(const ushort4*)(vfb + (size_t)sc * 96 + c4 * 4);
        a0 += w * bf2f(v.x);
        a1 += w * bf2f(v.y);
        a2 += w * bf2f(v.z);
        a3 += w * bf2f(v.w);
    }
    *(float4*)(out + (size_t)r * 96 + c4 * 4) = make_float4(a0, a1, a2, a3);
}

// ---------------------------------------------------------------------------
extern "C" void kernel_launch(void* const* d_in, const int* in_sizes, int n_in,
                              void* d_out, int out_size, void* d_ws, size_t ws_size,
                              hipStream_t stream) {
    const float* x      = (const float*)d_in[0];
    const float* coords = (const float*)d_in[1];
    const float* Wq1 = (const float*)d_in[2];
    const float* gq1 = (const float*)d_in[3];
    const float* bq1 = (const float*)d_in[4];
    const float* Wq2 = (const float*)d_in[5];
    const float* gq2 = (const float*)d_in[6];
    const float* bq2 = (const float*)d_in[7];
    const float* Wv  = (const float*)d_in[8];
    const float* gv  = (const float*)d_in[9];
    const float* bv  = (const float*)d_in[10];
    const float* Wp1 = (const float*)d_in[11];
    const float* gp1 = (const float*)d_in[12];
    const float* bp1 = (const float*)d_in[13];
    const float* Wp2 = (const float*)d_in[14];
    const float* gp2 = (const float*)d_in[15];
    const float* bp2 = (const float*)d_in[16];
    const float* W1  = (const float*)d_in[17];
    const float* b1  = (const float*)d_in[18];
    const float* W2  = (const float*)d_in[19];
    const float* b2  = (const float*)d_in[20];
    const float* g_out = (const float*)d_in[21];
    const float* b_out = (const float*)d_in[22];
    const int* kmaps = (const int*)d_in[23];
    float* out = (float*)d_out;

    char* ws = (char*)d_ws;
    int*   srcOf  = (int*)ws;                        //  0        + 17,200,000
    float* rowAbs = (float*)(ws + 17200000);         //           +    400,000
    u16*   xb     = (u16*)(ws + 17600000);           //           + 19,200,000
    u16*   bufQb  = (u16*)(ws + 36800000);           //           + 19,200,000
    u16*   bufVb  = (u16*)(ws + 56000000);           //           + 19,200,000
    u16*   bufAb  = (u16*)(ws + 75200000);           //           + 19,200,000
    u16*   vfb    = (u16*)(ws + 75200000);           // overlays bufAb (dead after conv4)
    float* pescr  = (float*)(ws + 17600000);         // overlays xb+bufQb (dead by pe1)
    u16*   wbuf   = (u16*)(ws + 17600000);           // overlays pescr (dead after pe2)
    float* qf     = (float*)(ws + 94400000);         //           +  1,600,000
    float* peb    = (float*)(ws + 96000000);         //           +  1,600,000
    u16*   Wq1p   = (u16*)(ws + 97600000);           //           +    552,960
    u16*   Wvp    = (u16*)(ws + 98152960);           //           +    552,960
    u16*   Wq2t   = (u16*)(ws + 98705920);           //           +     82,944
    u16*   w1b    = (u16*)(ws + 98788864);           //           +      6,144
    u16*   w2b    = (u16*)(ws + 98795008);           //           +      3,072
    float* stats  = (float*)(ws + 98798080);         //           +      4,608

    hipMemsetAsync(srcOf, 0xFF, (size_t)K_ * N_ * 4, stream);  // -1
    hipMemsetAsync(stats, 0, 6 * 192 * 4, stream);

    k_build_srcof<<<(K_ * M_ + 255) / 256, 256, 0, stream>>>(kmaps, srcOf);
    k_rowabs_cvt<<<N_ / 4, 256, 0, stream>>>(x, rowAbs, xb);
    k_wt96p<<<(KC_ * 9216 + 255) / 256, 256, 0, stream>>>(Wq1, Wq1p);
    k_wt96p<<<(KC_ * 9216 + 255) / 256, 256, 0, stream>>>(Wv, Wvp);
    k_wt4<<<(KC_ * 1536 + 255) / 256, 256, 0, stream>>>(Wq2, Wq2t);
    k_w12b<<<12, 256, 0, stream>>>(W1, W2, w1b, w2b);

    const int cbD  = (N_ + 191) / 192;   // 521
    const int cb4  = (N_ + 127) / 128;   // 782
    const int eb96 = N_ * 96 / 256;      // 37500
    const int eb4  = (N_ * 4 + 255) / 256;

    // both convs + their BN stats in one pass
    k_conv96_dual<<<cbD, 384, 0, stream>>>(xb, Wq1p, Wvp, srcOf, bufQb, bufVb,
                                           stats + 0 * 192, stats + 4 * 192);

    // q-branch: bn+relu -> conv4 -> bn
    k_bnapply96_b2b<0><<<eb96, 256, 0, stream>>>(bufQb, stats + 0 * 192, gq1, bq1, nullptr, bufAb);
    k_conv4_mfma<<<cb4, 256, 0, stream>>>(bufAb, Wq2t, srcOf, qf);
    k_bnstats4<<<512, 256, 0, stream>>>(qf, stats + 1 * 192);
    k_bnapply<4, 0><<<eb4, 256, 0, stream>>>(qf, stats + 1 * 192, gq2, bq2, nullptr);

    // pe chain (pescr overlays xb+bufQb, both dead by now)
    k_pe1<<<eb96, 256, 0, stream>>>(coords, Wp1, pescr);
    k_bnstats96<<<512, 192, 0, stream>>>(pescr, stats + 2 * 192);
    k_bnapply<96, 0><<<eb96, 256, 0, stream>>>(pescr, stats + 2 * 192, gp1, bp1, nullptr);
    k_pe2<<<eb4, 256, 0, stream>>>(pescr, Wp2, peb);
    k_bnstats4<<<512, 256, 0, stream>>>(peb, stats + 3 * 192);
    k_bnapply<4, 0><<<eb4, 256, 0, stream>>>(peb, stats + 3 * 192, gp2, bp2, nullptr);

    // v-branch: bn+relu+pe -> vfb (bf16; overlays bufAb after conv4)
    k_bnapply96_b2b<1><<<eb96, 256, 0, stream>>>(bufVb, stats + 4 * 192, gv, bv, peb, vfb);

    // attention
    k_attn_logits_mfma<<<N_ / 32, 256, 0, stream>>>(qf, srcOf, rowAbs, w1b, b1, w2b, b2, wbuf);
    k_attn_gather<<<(N_ * 24) / 256, 256, 0, stream>>>(vfb, wbuf, srcOf, out);

    // out = relu(bn(out)) + x
    k_bnstats96<<<512, 192, 0, stream>>>(out, stats + 5 * 192);
    k_bnapply<96, 2><<<eb96, 256, 0, stream>>>(out, stats + 5 * 192, g_out, b_out, x);
}